// Round 7
// baseline (1499.528 us; speedup 1.0000x reference)
//
#include <hip/hip_runtime.h>
#include <hip/hip_bf16.h>
#include <hip/hip_cooperative_groups.h>

namespace cg = cooperative_groups;

// ---------------------------------------------------------------------------
// AttentionHeteroConv. R14 = R13 with the CSR chain (hist+scan+fill: 3
// launches, one of which ran 2 blocks on an idle GPU) collapsed into ONE
// cooperative kernel (grid-stride hist -> grid.sync -> parallel 3-phase
// exclusive scan -> grid.sync -> grid-stride fill). Runtime fallback to the
// R13 path if cooperative launch is rejected. attn/transform/outproj
// unchanged (R13-proven: per-direction attn dispatches keep gather L3-hot).
// 5 launches total.
// ---------------------------------------------------------------------------

#define C 128
#define NHEAD 4
#define DH 32
#define QK_SCALE 0.17677669529663687f  // 1/sqrt(32)

typedef __attribute__((ext_vector_type(8))) short bf16x8;
typedef __attribute__((ext_vector_type(4))) short short4v;
typedef __attribute__((ext_vector_type(2))) short short2v;
typedef __attribute__((ext_vector_type(4))) float f32x4;

__device__ __forceinline__ short f2bf(float f) {
    unsigned u = __float_as_uint(f);
    unsigned r = u + 0x7FFFu + ((u >> 16) & 1u);   // round-to-nearest-even
    return (short)(r >> 16);
}

// ---------------------------------------------------------------------------
// K1: transform (+prep tail blocks). Blocks [0,TB): 64-row transform tiles.
// Blocks [TB,TB+96): wip2bf. Blocks [TB+96,...): zero curA/curB.
// ---------------------------------------------------------------------------
__global__ __launch_bounds__(256, 2) void transform_prep_kernel(
    const float* __restrict__ xu, const float* __restrict__ xi,
    int NU, int NTOT,
    const float* __restrict__ Wnb, const float* __restrict__ bnb,
    const float* __restrict__ Wself, const float* __restrict__ bself,
    float* __restrict__ h, float* __restrict__ selfout,
    const float* __restrict__ Wip, unsigned* __restrict__ img,
    int* __restrict__ curA, int nA, int* __restrict__ curB, int nB, int TB)
{
    const int tid = threadIdx.x;

    if ((int)blockIdx.x >= TB) {
        int bid2 = (int)blockIdx.x - TB;
        if (bid2 < 96) {
            // wip2bf: Wip fp32 [384][128] -> bf16 image [ks][384][32]
            int id = bid2 * 256 + tid;           // 24576 pair-slots
            int ks = id / (384 * 16);
            int rem = id - ks * (384 * 16);
            int n = rem >> 4, kk = rem & 15;
            float a = Wip[(size_t)n * C + ks * 32 + kk * 2 + 0];
            float b = Wip[(size_t)n * C + ks * 32 + kk * 2 + 1];
            unsigned pa = ((unsigned)(unsigned short)f2bf(a))
                        | (((unsigned)(unsigned short)f2bf(b)) << 16);
            img[(size_t)ks * 6144 + n * 16 + kk] = pa;
        } else {
            int i = (bid2 - 96) * 256 + tid;
            if (i < nA) curA[i] = 0;
            else if (i < nA + nB) curB[i - nA] = 0;
        }
        return;
    }

    __shared__ float As[64 * 132];   // 33792 B
    __shared__ float Bs[256 * 36];   // 36864 B
    __shared__ float biasS[256];

    const int row0 = blockIdx.x * 64;

    biasS[tid] = (tid < 128) ? bnb[tid] : bself[tid - 128];

#pragma unroll
    for (int i = 0; i < 8; i++) {
        int id = tid + i * 256;
        int r = id >> 5, c4 = id & 31;
        int row = row0 + r;
        float4 v = make_float4(0.f, 0.f, 0.f, 0.f);
        if (row < NTOT) {
            v = (row < NU) ? ((const float4*)xu)[(size_t)row * 32 + c4]
                           : ((const float4*)xi)[(size_t)(row - NU) * 32 + c4];
        }
        *(float4*)&As[r * 132 + c4 * 4] = v;
    }

    const int tm = tid >> 5;   // 0..7
    const int tn = tid & 31;   // 0..31

    float acc[8][8];
#pragma unroll
    for (int m = 0; m < 8; m++)
#pragma unroll
        for (int j = 0; j < 8; j++) acc[m][j] = 0.f;

    for (int ks = 0; ks < 4; ks++) {
        __syncthreads();
#pragma unroll
        for (int i = 0; i < 8; i++) {
            int id = tid + i * 256;          // 2048 = 256 n x 8 q
            int n = id >> 3, q = id & 7;
            const float4* src = (n < 128)
                ? &((const float4*)Wnb)[(size_t)n * 32 + ks * 8 + q]
                : &((const float4*)Wself)[(size_t)(n - 128) * 32 + ks * 8 + q];
            *(float4*)&Bs[n * 36 + q * 4] = *src;
        }
        __syncthreads();

        for (int k4 = 0; k4 < 8; k4++) {
            float4 a[8];
#pragma unroll
            for (int m = 0; m < 8; m++)
                a[m] = *(const float4*)&As[(tm * 8 + m) * 132 + ks * 32 + k4 * 4];
            float4 b[8];
#pragma unroll
            for (int j = 0; j < 8; j++)
                b[j] = *(const float4*)&Bs[(tn + 32 * j) * 36 + k4 * 4];
#pragma unroll
            for (int m = 0; m < 8; m++) {
                float4 av = a[m];
#pragma unroll
                for (int j = 0; j < 8; j++) {
                    float4 bv = b[j];
                    acc[m][j] += av.x * bv.x + av.y * bv.y
                               + av.z * bv.z + av.w * bv.w;
                }
            }
        }
    }

#pragma unroll
    for (int m = 0; m < 8; m++) {
        int row = row0 + tm * 8 + m;
        if (row < NTOT) {
#pragma unroll
            for (int j = 0; j < 8; j++) {
                int jj = tn + 32 * j;
                float v = acc[m][j] + biasS[jj];
                if (j < 4) h[(size_t)row * C + jj] = v;
                else       selfout[(size_t)row * C + (jj - 128)] = v;
            }
        }
    }
}

// ---------------------------------------------------------------------------
// K2 (cooperative): hist + exclusive scan + fill, one launch.
// 2048 blocks x 256. Blocks 0..1023 scan curA, 1024..2047 scan curB
// (1 element/thread; nA,nB <= 262144 assumed -- 50000 here).
// ---------------------------------------------------------------------------
__global__ __launch_bounds__(256, 8) void graph_build_kernel(
    const int* __restrict__ dstA, const int* __restrict__ srcA, int nEA,
    int* __restrict__ curA, unsigned short* __restrict__ csrA, int nA,
    const int* __restrict__ dstB, const int* __restrict__ srcB, int nEB,
    int* __restrict__ curB, unsigned short* __restrict__ csrB, int nB,
    int* __restrict__ partials)
{
    cg::grid_group grid = cg::this_grid();
    const int tid = threadIdx.x;
    const int bid = (int)blockIdx.x;
    const int gsz = (int)gridDim.x * 256;
    const int gid = bid * 256 + tid;

    // ---- phase 1: histogram (cur arrays pre-zeroed by transform_prep) ----
    for (int i = gid; i < nEA + nEB; i += gsz) {
        if (i < nEA) atomicAdd(&curA[dstA[i]], 1);
        else         atomicAdd(&curB[dstB[i - nEA]], 1);
    }
    grid.sync();

    // ---- phase 2a: per-block scan (256 elems), store block totals ----
    const bool isB = (bid >= 1024);
    int* cur = isB ? curB : curA;
    const int n = isB ? nB : nA;
    int* part = partials + (isB ? 1024 : 0);
    const int bl = isB ? bid - 1024 : bid;
    const int idx = bl * 256 + tid;
    const int lane = tid & 63, wv = tid >> 6;

    int v = (idx < n) ? cur[idx] : 0;
    int x = v;
#pragma unroll
    for (int d = 1; d < 64; d <<= 1) {
        int t = __shfl_up(x, d, 64);
        if (lane >= d) x += t;
    }
    __shared__ int wsum[4];
    if (lane == 63) wsum[wv] = x;
    __syncthreads();
    int wpre = 0;
#pragma unroll
    for (int w = 0; w < 4; w++) wpre += (w < wv) ? wsum[w] : 0;
    const int excl = x - v + wpre;                    // exclusive within block
    if (tid == 0) part[bl] = wsum[0] + wsum[1] + wsum[2] + wsum[3];
    grid.sync();

    // ---- phase 2b: blocks 0,1 scan the 1024 block-totals in place ----
    if (bid < 2) {
        int* p = partials + bid * 1024;
        int pv0 = p[tid * 4 + 0], pv1 = p[tid * 4 + 1];
        int pv2 = p[tid * 4 + 2], pv3 = p[tid * 4 + 3];
        int s0 = pv0, s1 = s0 + pv1, s2 = s1 + pv2, s3 = s2 + pv3;
        int xx = s3;
#pragma unroll
        for (int d = 1; d < 64; d <<= 1) {
            int t = __shfl_up(xx, d, 64);
            if (lane >= d) xx += t;
        }
        __shared__ int wsum2[4];
        if (lane == 63) wsum2[wv] = xx;
        __syncthreads();
        int wpre2 = 0;
#pragma unroll
        for (int w = 0; w < 4; w++) wpre2 += (w < wv) ? wsum2[w] : 0;
        int base = xx - s3 + wpre2;
        p[tid * 4 + 0] = base;
        p[tid * 4 + 1] = base + s0;
        p[tid * 4 + 2] = base + s1;
        p[tid * 4 + 3] = base + s2;
    }
    grid.sync();

    // ---- phase 2c: write final exclusive scan ----
    if (idx < n) cur[idx] = excl + part[bl];
    grid.sync();

    // ---- phase 3: fill (cur becomes inclusive, as attn expects) ----
    for (int i = gid; i < nEA + nEB; i += gsz) {
        if (i < nEA) {
            int p2 = atomicAdd(&curA[dstA[i]], 1);
            csrA[p2] = (unsigned short)srcA[i];
        } else {
            int j = i - nEA;
            int p2 = atomicAdd(&curB[dstB[j]], 1);
            csrB[p2] = (unsigned short)srcB[j];
        }
    }
}

// ---------------------------------------------------------------------------
// Fallback path (R13): hist2 + scan2 + fill2, used only if the cooperative
// launch is rejected at capture time.
// ---------------------------------------------------------------------------
__global__ __launch_bounds__(256) void hist2_kernel(
    const int* __restrict__ dstA, int nA, int* __restrict__ curA,
    const int* __restrict__ dstB, int nB, int* __restrict__ curB)
{
    int i = blockIdx.x * 256 + threadIdx.x;
    if (i < nA) atomicAdd(&curA[dstA[i]], 1);
    else if (i < nA + nB) atomicAdd(&curB[dstB[i - nA]], 1);
}

__global__ __launch_bounds__(1024) void scan2_kernel(
    int* __restrict__ curA, int nA, int* __restrict__ curB, int nB)
{
    int* cur = (blockIdx.x == 0) ? curA : curB;
    const int n = (blockIdx.x == 0) ? nA : nB;

    __shared__ int wsum[16];
    __shared__ int carryS;
    const int tid = threadIdx.x, lane = tid & 63, wv = tid >> 6;
    if (tid == 0) carryS = 0;
    __syncthreads();
    for (int base = 0; base < n; base += 4096) {
        int i0 = base + tid * 4;
        int v0 = 0, v1 = 0, v2 = 0, v3 = 0;
        if (i0 + 3 < n) {
            int4 t = *(const int4*)&cur[i0];
            v0 = t.x; v1 = t.y; v2 = t.z; v3 = t.w;
        } else {
            if (i0 < n) v0 = cur[i0];
            if (i0 + 1 < n) v1 = cur[i0 + 1];
            if (i0 + 2 < n) v2 = cur[i0 + 2];
            if (i0 + 3 < n) v3 = cur[i0 + 3];
        }
        int s1 = v0 + v1, s2 = s1 + v2, s3 = s2 + v3;
        int x = s3;
#pragma unroll
        for (int d = 1; d < 64; d <<= 1) {
            int t = __shfl_up(x, d, 64);
            if (lane >= d) x += t;
        }
        if (lane == 63) wsum[wv] = x;
        int carry = carryS;
        __syncthreads();
        int wpre = 0;
#pragma unroll
        for (int w2 = 0; w2 < 16; w2++) wpre += (w2 < wv) ? wsum[w2] : 0;
        int excl = x - s3 + wpre + carry;
        if (i0 + 3 < n) {
            int4 st; st.x = excl; st.y = excl + v0; st.z = excl + s1; st.w = excl + s2;
            *(int4*)&cur[i0] = st;
        } else {
            if (i0 < n) cur[i0] = excl;
            if (i0 + 1 < n) cur[i0 + 1] = excl + v0;
            if (i0 + 2 < n) cur[i0 + 2] = excl + s1;
            if (i0 + 3 < n) cur[i0 + 3] = excl + s2;
        }
        __syncthreads();
        if (tid == 0) {
            int t = 0;
#pragma unroll
            for (int w2 = 0; w2 < 16; w2++) t += wsum[w2];
            carryS = carry + t;
        }
        __syncthreads();
    }
}

__global__ __launch_bounds__(256) void fill2_kernel(
    const int* __restrict__ srcA, const int* __restrict__ dstA, int nA,
    int* __restrict__ curA, unsigned short* __restrict__ csrA,
    const int* __restrict__ srcB, const int* __restrict__ dstB, int nB,
    int* __restrict__ curB, unsigned short* __restrict__ csrB)
{
    int i = blockIdx.x * 256 + threadIdx.x;
    if (i < nA) {
        int p = atomicAdd(&curA[dstA[i]], 1);
        csrA[p] = (unsigned short)srcA[i];
    } else if (i < nA + nB) {
        int j = i - nA;
        int p = atomicAdd(&curB[dstB[j]], 1);
        csrB[p] = (unsigned short)srcB[j];
    }
}

// ---------------------------------------------------------------------------
// K4: fused gather-aggregate + bf16-MFMA qkv + in-register attention.
// R11-proven: 4 nodes/block, one direction per dispatch (keeps the gather
// stream L3-resident), 8 blocks/CU. ushort CSR.
// ---------------------------------------------------------------------------
#define ATN 4

__global__ __launch_bounds__(256, 8) void attn_fused_kernel(
    const float* __restrict__ h_src, const unsigned short* __restrict__ csr,
    const int* __restrict__ cur, const float* __restrict__ selfF,
    const short* __restrict__ wipbf, const float* __restrict__ bip,
    float* __restrict__ omean_g, int n_nodes)
{
    __shared__ char Ash[16 * 272];   // bf16 A tile [16 rows][136 bf16]
    __shared__ float cinv[ATN];

    const int tid = threadIdx.x;
    const int lane = tid & 63;
    const int wv = tid >> 6;
    const int node0 = blockIdx.x * ATN;

    // ---- P0a: self rows (A row node*4+0, bf16) ----
    if (tid < 128) {
        int r = tid >> 5, c4 = tid & 31;
        int node = node0 + r;
        float4 v = make_float4(0.f, 0.f, 0.f, 0.f);
        if (node < n_nodes) v = ((const float4*)selfF)[(size_t)node * 32 + c4];
        short4v b;
        b.x = f2bf(v.x); b.y = f2bf(v.y); b.z = f2bf(v.z); b.w = f2bf(v.w);
        *(short4v*)(Ash + (r * 4) * 272 + c4 * 8) = b;
    }

    // ---- P0b: gather max/min/sum -> A rows wv*4+{1,2,3} (one node/wave) ----
    {
        const float2* h2 = (const float2*)h_src;
        int node = node0 + wv;
        float2 vs = make_float2(0.f, 0.f);
        float2 vmx = make_float2(-3.4e38f, -3.4e38f);
        float2 vmn = make_float2(3.4e38f, 3.4e38f);
        int deg = 0;
        if (node < n_nodes) {
            int start = (node == 0) ? 0 : cur[node - 1];
            int end = cur[node];
            deg = end - start;
            int e = start;
            for (; e + 8 <= end; e += 8) {
                float2 v[8];
#pragma unroll
                for (int i = 0; i < 8; i++) {
                    int s = csr[e + i];
                    v[i] = h2[(size_t)s * 64 + lane];
                }
#pragma unroll
                for (int i = 0; i < 8; i++) {
                    vs.x += v[i].x; vs.y += v[i].y;
                    vmx.x = fmaxf(vmx.x, v[i].x); vmx.y = fmaxf(vmx.y, v[i].y);
                    vmn.x = fminf(vmn.x, v[i].x); vmn.y = fminf(vmn.y, v[i].y);
                }
            }
            if (e < end) {   // masked full-width tail: one latency round
                int last = end - 1;
                float2 v[8];
#pragma unroll
                for (int i = 0; i < 8; i++) {
                    int idx = e + i;
                    int s = csr[(idx <= last) ? idx : last];
                    v[i] = h2[(size_t)s * 64 + lane];
                }
#pragma unroll
                for (int i = 0; i < 8; i++) {
                    if (e + i <= last) {   // wave-uniform
                        vs.x += v[i].x; vs.y += v[i].y;
                        vmx.x = fmaxf(vmx.x, v[i].x); vmx.y = fmaxf(vmx.y, v[i].y);
                        vmn.x = fminf(vmn.x, v[i].x); vmn.y = fminf(vmn.y, v[i].y);
                    }
                }
            }
        }
        if (deg == 0) {
            vmx = make_float2(0.f, 0.f);
            vmn = make_float2(0.f, 0.f);
        }
        short2v p;
        p.x = f2bf(vmx.x); p.y = f2bf(vmx.y);
        *(short2v*)(Ash + (wv * 4 + 1) * 272 + lane * 4) = p;
        p.x = f2bf(vmn.x); p.y = f2bf(vmn.y);
        *(short2v*)(Ash + (wv * 4 + 2) * 272 + lane * 4) = p;
        p.x = f2bf(vs.x); p.y = f2bf(vs.y);
        *(short2v*)(Ash + (wv * 4 + 3) * 272 + lane * 4) = p;
        if (lane == 0) cinv[wv] = 1.f / (float)max(deg, 1);
    }
    __syncthreads();   // the ONLY barrier

    // ---- P1: MFMA qkv for head wv only (M=16, N=6x16 tiles, K=128) ----
    const int quad = lane >> 4;      // node within block
    const int col16 = lane & 15;     // head-dim coordinate (cols c and c+16)

    f32x4 acc[6];
#pragma unroll
    for (int t = 0; t < 6; t++) acc[t] = (f32x4){0.f, 0.f, 0.f, 0.f};

#pragma unroll
    for (int ks = 0; ks < 4; ks++) {
        bf16x8 af = *(const bf16x8*)(Ash + col16 * 272 + ks * 64 + quad * 16);
#pragma unroll
        for (int t = 0; t < 6; t++) {
            int nb = wv * 32 + (t & 1) * 16 + (t >> 1) * 128 + col16;
            bf16x8 bfr = *(const bf16x8*)((const char*)wipbf
                          + (size_t)ks * 24576 + (size_t)nb * 64 + quad * 16);
            acc[t] = __builtin_amdgcn_mfma_f32_16x16x32_bf16(af, bfr, acc[t], 0, 0, 0);
        }
    }

    // ---- P2: in-register attention for head wv, node quad ----
    const float ci = cinv[quad];
    const float cis = ci * QK_SCALE;

    const float bq0 = bip[wv * 32 + col16];
    const float bq1 = bip[wv * 32 + 16 + col16];
    const float bk0 = bip[128 + wv * 32 + col16];
    const float bk1 = bip[128 + wv * 32 + 16 + col16];
    const float bv0 = bip[256 + wv * 32 + col16];
    const float bv1 = bip[256 + wv * 32 + 16 + col16];
    const float bq0s = bq0 * QK_SCALE;
    const float bq1s = bq1 * QK_SCALE;

    float k0[5], k1[5];
#pragma unroll
    for (int s = 0; s < 4; s++) { k0[s] = acc[2][s] + bk0; k1[s] = acc[3][s] + bk1; }
    k0[4] = fmaf(acc[2][3], ci, bk0);
    k1[4] = fmaf(acc[3][3], ci, bk1);

    float wj[5] = {0.f, 0.f, 0.f, 0.f, 0.f};
#pragma unroll
    for (int i = 0; i < 5; i++) {
        float qi0 = (i < 4) ? fmaf(acc[0][i], QK_SCALE, bq0s)
                            : fmaf(acc[0][3], cis, bq0s);
        float qi1 = (i < 4) ? fmaf(acc[1][i], QK_SCALE, bq1s)
                            : fmaf(acc[1][3], cis, bq1s);
        float sv[5];
#pragma unroll
        for (int j = 0; j < 5; j++) sv[j] = qi0 * k0[j] + qi1 * k1[j];
#pragma unroll
        for (int j = 0; j < 5; j++) {
            sv[j] += __shfl_xor(sv[j], 1, 16);
            sv[j] += __shfl_xor(sv[j], 2, 16);
            sv[j] += __shfl_xor(sv[j], 4, 16);
            sv[j] += __shfl_xor(sv[j], 8, 16);
        }
        float m = sv[0];
#pragma unroll
        for (int j = 1; j < 5; j++) m = fmaxf(m, sv[j]);
        float e[5], l = 0.f;
#pragma unroll
        for (int j = 0; j < 5; j++) { e[j] = __expf(sv[j] - m); l += e[j]; }
        float inv = 0.2f / l;   // fold token-mean
#pragma unroll
        for (int j = 0; j < 5; j++) wj[j] = fmaf(e[j], inv, wj[j]);
    }

    float o0 = 0.f, o1 = 0.f;
#pragma unroll
    for (int j = 0; j < 5; j++) {
        float v0 = (j < 4) ? (acc[4][j] + bv0) : fmaf(acc[4][3], ci, bv0);
        float v1 = (j < 4) ? (acc[5][j] + bv1) : fmaf(acc[5][3], ci, bv1);
        o0 = fmaf(wj[j], v0, o0);
        o1 = fmaf(wj[j], v1, o1);
    }

    int node = node0 + quad;
    if (node < n_nodes) {
        omean_g[(size_t)node * C + wv * 32 + col16] = o0;
        omean_g[(size_t)node * C + wv * 32 + 16 + col16] = o1;
    }
}

// ---------------------------------------------------------------------------
// K5: out = self(d_out) + omean @ Wop^T + bop. 64-row blocks, 8x4 tiles.
// ---------------------------------------------------------------------------
__global__ __launch_bounds__(256, 3) void outproj_kernel(
    const float* __restrict__ omean_g, const float* __restrict__ Wop,
    const float* __restrict__ bop, float* __restrict__ out, int M)
{
    __shared__ float As[64 * 132];   // 33792 B
    __shared__ float Bs[128 * 36];   // 18432 B
    __shared__ float bopS[C];

    const int tid = threadIdx.x;
    const int m0 = blockIdx.x * 64;

    if (tid < C) bopS[tid] = bop[tid];

#pragma unroll
    for (int i = 0; i < 8; i++) {
        int id = tid + i * 256;
        int r = id >> 5, c4 = id & 31;
        float4 v = make_float4(0.f, 0.f, 0.f, 0.f);
        if (m0 + r < M) v = ((const float4*)omean_g)[(size_t)(m0 + r) * 32 + c4];
        *(float4*)&As[r * 132 + c4 * 4] = v;
    }

    const int tn = tid & 31;
    const int tm = tid >> 5;
    float acc[8][4];
#pragma unroll
    for (int m = 0; m < 8; m++)
#pragma unroll
        for (int j = 0; j < 4; j++) acc[m][j] = 0.f;

    for (int ks = 0; ks < 4; ks++) {
        __syncthreads();
#pragma unroll
        for (int i = 0; i < 4; i++) {
            int id = tid + i * 256;          // 1024 = 128 n x 8 q
            int n = id >> 3, q = id & 7;
            float4 w = ((const float4*)Wop)[(size_t)n * 32 + ks * 8 + q];
            *(float4*)&Bs[n * 36 + q * 4] = w;
        }
        __syncthreads();

        for (int k4 = 0; k4 < 8; k4++) {
            float4 a[8];
#pragma unroll
            for (int m = 0; m < 8; m++)
                a[m] = *(const float4*)&As[(tm * 8 + m) * 132 + ks * 32 + k4 * 4];
            float4 b[4];
#pragma unroll
            for (int j = 0; j < 4; j++)
                b[j] = *(const float4*)&Bs[(tn + 32 * j) * 36 + k4 * 4];
#pragma unroll
            for (int m = 0; m < 8; m++) {
                float4 av = a[m];
#pragma unroll
                for (int j = 0; j < 4; j++) {
                    float4 bv = b[j];
                    acc[m][j] += av.x * bv.x + av.y * bv.y
                               + av.z * bv.z + av.w * bv.w;
                }
            }
        }
    }

#pragma unroll
    for (int m = 0; m < 8; m++) {
        int row = m0 + tm * 8 + m;
        if (row < M) {
#pragma unroll
            for (int j = 0; j < 4; j++) {
                int col = tn + 32 * j;
                float* o = &out[(size_t)row * C + col];
                *o += acc[m][j] + bopS[col];
            }
        }
    }
}

// ---------------------------------------------------------------------------
extern "C" void kernel_launch(void* const* d_in, const int* in_sizes, int n_in,
                              void* d_out, int out_size, void* d_ws, size_t ws_size,
                              hipStream_t stream) {
    const float* x_user = (const float*)d_in[0];
    const float* x_item = (const float*)d_in[1];
    const int*   ei_u2i = (const int*)d_in[2];
    const int*   ei_i2u = (const int*)d_in[3];
    const float* W_nb   = (const float*)d_in[4];
    const float* b_nb   = (const float*)d_in[5];
    const float* W_self = (const float*)d_in[6];
    const float* b_self = (const float*)d_in[7];
    const float* Wip    = (const float*)d_in[8];
    const float* bip    = (const float*)d_in[9];
    const float* Wop    = (const float*)d_in[10];
    const float* bop    = (const float*)d_in[11];

    const int NU = in_sizes[0] / C;
    const int NI = in_sizes[1] / C;
    const int E1 = in_sizes[2] / 2;
    const int E2 = in_sizes[3] / 2;
    const int NTOT = NU + NI;

    float* out_user = (float*)d_out;
    float* out_item = out_user + (size_t)NU * C;

    // workspace: wipbf (24576 floats) | h (rc) | omean (rc)
    //          | curA (NI) | curB (NU) | csrA16 (E1) | csrB16 (E2) | partials
    float* ws = (float*)d_ws;
    short* wipbf     = (short*)ws;
    float* h_all     = ws + 24576;
    const size_t rc = (size_t)NTOT * C;
    float* omean_all = h_all + rc;
    int*   curA      = (int*)(omean_all + rc);     // item-side degrees (NI)
    int*   curB      = curA + NI;                  // user-side degrees (NU)
    unsigned short* csrA16 = (unsigned short*)(curB + NU);
    unsigned short* csrB16 = csrA16 + E1;
    int*   partials  = (int*)(csrB16 + E2);        // 2048 ints

    float* h_user = h_all;
    float* h_item = h_all + (size_t)NU * C;
    float* om_user = omean_all;
    float* om_item = omean_all + (size_t)NU * C;

    // K1: transform + prep (wip2bf + zero cur arrays)
    const int TB = (NTOT + 63) / 64;
    const int PB = 96 + (NTOT + 255) / 256;
    transform_prep_kernel<<<TB + PB, 256, 0, stream>>>(
        x_user, x_item, NU, NTOT, W_nb, b_nb, W_self, b_self,
        h_all, (float*)d_out, Wip, (unsigned*)wipbf, curA, NI, curB, NU, TB);

    // K2: cooperative hist+scan+fill (fallback: 3-kernel R13 path)
    {
        const int* dA = ei_u2i + E1; const int* sA = ei_u2i; int eA = E1; int na = NI;
        const int* dB = ei_i2u + E2; const int* sB = ei_i2u; int eB = E2; int nb = NU;
        void* args[] = { (void*)&dA, (void*)&sA, (void*)&eA,
                         (void*)&curA, (void*)&csrA16, (void*)&na,
                         (void*)&dB, (void*)&sB, (void*)&eB,
                         (void*)&curB, (void*)&csrB16, (void*)&nb,
                         (void*)&partials };
        hipError_t cerr = hipLaunchCooperativeKernel(
            (const void*)graph_build_kernel, dim3(2048), dim3(256), args, 0, stream);
        if (cerr != hipSuccess) {
            hist2_kernel<<<(E1 + E2 + 255) / 256, 256, 0, stream>>>(
                ei_u2i + E1, E1, curA, ei_i2u + E2, E2, curB);
            scan2_kernel<<<2, 1024, 0, stream>>>(curA, NI, curB, NU);
            fill2_kernel<<<(E1 + E2 + 255) / 256, 256, 0, stream>>>(
                ei_u2i, ei_u2i + E1, E1, curA, csrA16,
                ei_i2u, ei_i2u + E2, E2, curB, csrB16);
        }
    }

    // K3: direction B (item -> user)
    attn_fused_kernel<<<(NU + ATN - 1) / ATN, 256, 0, stream>>>(
        h_item, csrB16, curB, out_user, wipbf, bip, om_user, NU);

    // K4: direction A (user -> item)
    attn_fused_kernel<<<(NI + ATN - 1) / ATN, 256, 0, stream>>>(
        h_user, csrA16, curA, out_item, wipbf, bip, om_item, NI);

    // K5: output projection
    outproj_kernel<<<(NTOT + 63) / 64, 256, 0, stream>>>(
        omean_all, Wop, bop, (float*)d_out, NTOT);
}

// Round 8
// 672.817 us; speedup vs baseline: 2.2287x; 2.2287x over previous
//
#include <hip/hip_runtime.h>
#include <hip/hip_bf16.h>

// ---------------------------------------------------------------------------
// AttentionHeteroConv. R15 = R13 with bf16 gather arrays.
// R14 lesson: cooperative grid.sync costs ~240us per barrier on gfx950 --
// never replace a launch boundary with it. CSR chain back to R13's
// hist2/scan2/fill2.
// R15 change: h and self-feat stored as bf16 (ushort). attn's random-row
// gather was fabric-BW bound (FETCH 195MB ~= 111us at 1.76TB/s); halving
// bytes/row should halve it. Aggregation stays fp32 (unpack = 2 bit-ops per
// bf16 pair; max/min commute with monotone rounding; sum error ~ existing
// bf16-rounding error). attn self-row load is now conversion-free.
// 7 launches.
// ---------------------------------------------------------------------------

#define C 128
#define NHEAD 4
#define DH 32
#define QK_SCALE 0.17677669529663687f  // 1/sqrt(32)

typedef __attribute__((ext_vector_type(8))) short bf16x8;
typedef __attribute__((ext_vector_type(4))) short short4v;
typedef __attribute__((ext_vector_type(2))) short short2v;
typedef __attribute__((ext_vector_type(4))) float f32x4;

__device__ __forceinline__ short f2bf(float f) {
    unsigned u = __float_as_uint(f);
    unsigned r = u + 0x7FFFu + ((u >> 16) & 1u);   // round-to-nearest-even
    return (short)(r >> 16);
}

// ---------------------------------------------------------------------------
// K1: transform (+prep tail blocks). Blocks [0,TB): 64-row transform tiles.
// Blocks [TB,TB+96): wip2bf. Blocks [TB+96,...): zero curA/curB.
// h and self-feat written as bf16; self-feat also fp32 into d_out.
// ---------------------------------------------------------------------------
__global__ __launch_bounds__(256, 2) void transform_prep_kernel(
    const float* __restrict__ xu, const float* __restrict__ xi,
    int NU, int NTOT,
    const float* __restrict__ Wnb, const float* __restrict__ bnb,
    const float* __restrict__ Wself, const float* __restrict__ bself,
    unsigned short* __restrict__ h_bf, unsigned short* __restrict__ self_bf,
    float* __restrict__ selfout,
    const float* __restrict__ Wip, unsigned* __restrict__ img,
    int* __restrict__ curA, int nA, int* __restrict__ curB, int nB, int TB)
{
    const int tid = threadIdx.x;

    if ((int)blockIdx.x >= TB) {
        int bid2 = (int)blockIdx.x - TB;
        if (bid2 < 96) {
            // wip2bf: Wip fp32 [384][128] -> bf16 image [ks][384][32]
            int id = bid2 * 256 + tid;           // 24576 pair-slots
            int ks = id / (384 * 16);
            int rem = id - ks * (384 * 16);
            int n = rem >> 4, kk = rem & 15;
            float a = Wip[(size_t)n * C + ks * 32 + kk * 2 + 0];
            float b = Wip[(size_t)n * C + ks * 32 + kk * 2 + 1];
            unsigned pa = ((unsigned)(unsigned short)f2bf(a))
                        | (((unsigned)(unsigned short)f2bf(b)) << 16);
            img[(size_t)ks * 6144 + n * 16 + kk] = pa;
        } else {
            int i = (bid2 - 96) * 256 + tid;
            if (i < nA) curA[i] = 0;
            else if (i < nA + nB) curB[i - nA] = 0;
        }
        return;
    }

    __shared__ float As[64 * 132];   // 33792 B
    __shared__ float Bs[256 * 36];   // 36864 B
    __shared__ float biasS[256];

    const int row0 = blockIdx.x * 64;

    biasS[tid] = (tid < 128) ? bnb[tid] : bself[tid - 128];

#pragma unroll
    for (int i = 0; i < 8; i++) {
        int id = tid + i * 256;
        int r = id >> 5, c4 = id & 31;
        int row = row0 + r;
        float4 v = make_float4(0.f, 0.f, 0.f, 0.f);
        if (row < NTOT) {
            v = (row < NU) ? ((const float4*)xu)[(size_t)row * 32 + c4]
                           : ((const float4*)xi)[(size_t)(row - NU) * 32 + c4];
        }
        *(float4*)&As[r * 132 + c4 * 4] = v;
    }

    const int tm = tid >> 5;   // 0..7
    const int tn = tid & 31;   // 0..31

    float acc[8][8];
#pragma unroll
    for (int m = 0; m < 8; m++)
#pragma unroll
        for (int j = 0; j < 8; j++) acc[m][j] = 0.f;

    for (int ks = 0; ks < 4; ks++) {
        __syncthreads();
#pragma unroll
        for (int i = 0; i < 8; i++) {
            int id = tid + i * 256;          // 2048 = 256 n x 8 q
            int n = id >> 3, q = id & 7;
            const float4* src = (n < 128)
                ? &((const float4*)Wnb)[(size_t)n * 32 + ks * 8 + q]
                : &((const float4*)Wself)[(size_t)(n - 128) * 32 + ks * 8 + q];
            *(float4*)&Bs[n * 36 + q * 4] = *src;
        }
        __syncthreads();

        for (int k4 = 0; k4 < 8; k4++) {
            float4 a[8];
#pragma unroll
            for (int m = 0; m < 8; m++)
                a[m] = *(const float4*)&As[(tm * 8 + m) * 132 + ks * 32 + k4 * 4];
            float4 b[8];
#pragma unroll
            for (int j = 0; j < 8; j++)
                b[j] = *(const float4*)&Bs[(tn + 32 * j) * 36 + k4 * 4];
#pragma unroll
            for (int m = 0; m < 8; m++) {
                float4 av = a[m];
#pragma unroll
                for (int j = 0; j < 8; j++) {
                    float4 bv = b[j];
                    acc[m][j] += av.x * bv.x + av.y * bv.y
                               + av.z * bv.z + av.w * bv.w;
                }
            }
        }
    }

#pragma unroll
    for (int m = 0; m < 8; m++) {
        int row = row0 + tm * 8 + m;
        if (row < NTOT) {
#pragma unroll
            for (int j = 0; j < 8; j++) {
                int jj = tn + 32 * j;
                float v = acc[m][j] + biasS[jj];
                if (j < 4) {
                    h_bf[(size_t)row * C + jj] = (unsigned short)f2bf(v);
                } else {
                    selfout[(size_t)row * C + (jj - 128)] = v;
                    self_bf[(size_t)row * C + (jj - 128)] = (unsigned short)f2bf(v);
                }
            }
        }
    }
}

// ---------------------------------------------------------------------------
// Merged histogram over both edge lists.
// ---------------------------------------------------------------------------
__global__ __launch_bounds__(256) void hist2_kernel(
    const int* __restrict__ dstA, int nA, int* __restrict__ curA,
    const int* __restrict__ dstB, int nB, int* __restrict__ curB)
{
    int i = blockIdx.x * 256 + threadIdx.x;
    if (i < nA) atomicAdd(&curA[dstA[i]], 1);
    else if (i < nA + nB) atomicAdd(&curB[dstB[i - nA]], 1);
}

// ---------------------------------------------------------------------------
// Scan: 2 blocks (block 0 -> curA/nA, block 1 -> curB/nB), 1024 threads,
// 4 elems/thread.
// ---------------------------------------------------------------------------
__global__ __launch_bounds__(1024) void scan2_kernel(
    int* __restrict__ curA, int nA, int* __restrict__ curB, int nB)
{
    int* cur = (blockIdx.x == 0) ? curA : curB;
    const int n = (blockIdx.x == 0) ? nA : nB;

    __shared__ int wsum[16];
    __shared__ int carryS;
    const int tid = threadIdx.x, lane = tid & 63, wv = tid >> 6;
    if (tid == 0) carryS = 0;
    __syncthreads();
    for (int base = 0; base < n; base += 4096) {
        int i0 = base + tid * 4;
        int v0 = 0, v1 = 0, v2 = 0, v3 = 0;
        if (i0 + 3 < n) {
            int4 t = *(const int4*)&cur[i0];
            v0 = t.x; v1 = t.y; v2 = t.z; v3 = t.w;
        } else {
            if (i0 < n) v0 = cur[i0];
            if (i0 + 1 < n) v1 = cur[i0 + 1];
            if (i0 + 2 < n) v2 = cur[i0 + 2];
            if (i0 + 3 < n) v3 = cur[i0 + 3];
        }
        int s1 = v0 + v1, s2 = s1 + v2, s3 = s2 + v3;
        int x = s3;
#pragma unroll
        for (int d = 1; d < 64; d <<= 1) {
            int t = __shfl_up(x, d, 64);
            if (lane >= d) x += t;
        }
        if (lane == 63) wsum[wv] = x;
        int carry = carryS;
        __syncthreads();
        int wpre = 0;
#pragma unroll
        for (int w2 = 0; w2 < 16; w2++) wpre += (w2 < wv) ? wsum[w2] : 0;
        int excl = x - s3 + wpre + carry;
        if (i0 + 3 < n) {
            int4 st; st.x = excl; st.y = excl + v0; st.z = excl + s1; st.w = excl + s2;
            *(int4*)&cur[i0] = st;
        } else {
            if (i0 < n) cur[i0] = excl;
            if (i0 + 1 < n) cur[i0 + 1] = excl + v0;
            if (i0 + 2 < n) cur[i0 + 2] = excl + s1;
            if (i0 + 3 < n) cur[i0 + 3] = excl + s2;
        }
        __syncthreads();
        if (tid == 0) {
            int t = 0;
#pragma unroll
            for (int w2 = 0; w2 < 16; w2++) t += wsum[w2];
            carryS = carry + t;
        }
        __syncthreads();
    }
}

// ---------------------------------------------------------------------------
// Merged fill: CSR entries stored as ushort (node ids < 65536).
// ---------------------------------------------------------------------------
__global__ __launch_bounds__(256) void fill2_kernel(
    const int* __restrict__ srcA, const int* __restrict__ dstA, int nA,
    int* __restrict__ curA, unsigned short* __restrict__ csrA,
    const int* __restrict__ srcB, const int* __restrict__ dstB, int nB,
    int* __restrict__ curB, unsigned short* __restrict__ csrB)
{
    int i = blockIdx.x * 256 + threadIdx.x;
    if (i < nA) {
        int p = atomicAdd(&curA[dstA[i]], 1);
        csrA[p] = (unsigned short)srcA[i];
    } else if (i < nA + nB) {
        int j = i - nA;
        int p = atomicAdd(&curB[dstB[j]], 1);
        csrB[p] = (unsigned short)srcB[j];
    }
}

// ---------------------------------------------------------------------------
// K4: fused gather-aggregate + bf16-MFMA qkv + in-register attention.
// 4 nodes/block, one direction per dispatch, 8 blocks/CU.
// h is bf16: lane reads 1 uint (2 bf16) per row -> half the gather bytes.
// Unpack: x = asfloat(u<<16), y = asfloat(u & 0xFFFF0000).
// ---------------------------------------------------------------------------
#define ATN 4

__global__ __launch_bounds__(256, 8) void attn_fused_kernel(
    const unsigned short* __restrict__ h_bf, const unsigned short* __restrict__ csr,
    const int* __restrict__ cur, const unsigned short* __restrict__ self_bf,
    const short* __restrict__ wipbf, const float* __restrict__ bip,
    float* __restrict__ omean_g, int n_nodes)
{
    __shared__ char Ash[16 * 272];   // bf16 A tile [16 rows][136 bf16]
    __shared__ float cinv[ATN];

    const int tid = threadIdx.x;
    const int lane = tid & 63;
    const int wv = tid >> 6;
    const int node0 = blockIdx.x * ATN;

    // ---- P0a: self rows (A row node*4+0) -- already bf16, direct copy ----
    if (tid < 128) {
        int r = tid >> 5, c4 = tid & 31;
        int node = node0 + r;
        short4v b = {0, 0, 0, 0};
        if (node < n_nodes)
            b = *(const short4v*)(self_bf + (size_t)node * C + c4 * 4);
        *(short4v*)(Ash + (r * 4) * 272 + c4 * 8) = b;
    }

    // ---- P0b: gather max/min/sum -> A rows wv*4+{1,2,3} (one node/wave) ----
    {
        const unsigned* h2 = (const unsigned*)h_bf;   // 64 uints per row
        int node = node0 + wv;
        float2 vs = make_float2(0.f, 0.f);
        float2 vmx = make_float2(-3.4e38f, -3.4e38f);
        float2 vmn = make_float2(3.4e38f, 3.4e38f);
        int deg = 0;
        if (node < n_nodes) {
            int start = (node == 0) ? 0 : cur[node - 1];
            int end = cur[node];
            deg = end - start;
            int e = start;
            for (; e + 8 <= end; e += 8) {
                unsigned v[8];
#pragma unroll
                for (int i = 0; i < 8; i++) {
                    int s = csr[e + i];
                    v[i] = h2[(size_t)s * 64 + lane];
                }
#pragma unroll
                for (int i = 0; i < 8; i++) {
                    float fx = __uint_as_float(v[i] << 16);
                    float fy = __uint_as_float(v[i] & 0xFFFF0000u);
                    vs.x += fx; vs.y += fy;
                    vmx.x = fmaxf(vmx.x, fx); vmx.y = fmaxf(vmx.y, fy);
                    vmn.x = fminf(vmn.x, fx); vmn.y = fminf(vmn.y, fy);
                }
            }
            if (e < end) {   // masked full-width tail: one latency round
                int last = end - 1;
                unsigned v[8];
#pragma unroll
                for (int i = 0; i < 8; i++) {
                    int idx = e + i;
                    int s = csr[(idx <= last) ? idx : last];
                    v[i] = h2[(size_t)s * 64 + lane];
                }
#pragma unroll
                for (int i = 0; i < 8; i++) {
                    if (e + i <= last) {   // wave-uniform
                        float fx = __uint_as_float(v[i] << 16);
                        float fy = __uint_as_float(v[i] & 0xFFFF0000u);
                        vs.x += fx; vs.y += fy;
                        vmx.x = fmaxf(vmx.x, fx); vmx.y = fmaxf(vmx.y, fy);
                        vmn.x = fminf(vmn.x, fx); vmn.y = fminf(vmn.y, fy);
                    }
                }
            }
        }
        if (deg == 0) {
            vmx = make_float2(0.f, 0.f);
            vmn = make_float2(0.f, 0.f);
        }
        short2v p;
        p.x = f2bf(vmx.x); p.y = f2bf(vmx.y);
        *(short2v*)(Ash + (wv * 4 + 1) * 272 + lane * 4) = p;
        p.x = f2bf(vmn.x); p.y = f2bf(vmn.y);
        *(short2v*)(Ash + (wv * 4 + 2) * 272 + lane * 4) = p;
        p.x = f2bf(vs.x); p.y = f2bf(vs.y);
        *(short2v*)(Ash + (wv * 4 + 3) * 272 + lane * 4) = p;
        if (lane == 0) cinv[wv] = 1.f / (float)max(deg, 1);
    }
    __syncthreads();   // the ONLY barrier

    // ---- P1: MFMA qkv for head wv only (M=16, N=6x16 tiles, K=128) ----
    const int quad = lane >> 4;      // node within block
    const int col16 = lane & 15;     // head-dim coordinate (cols c and c+16)

    f32x4 acc[6];
#pragma unroll
    for (int t = 0; t < 6; t++) acc[t] = (f32x4){0.f, 0.f, 0.f, 0.f};

#pragma unroll
    for (int ks = 0; ks < 4; ks++) {
        bf16x8 af = *(const bf16x8*)(Ash + col16 * 272 + ks * 64 + quad * 16);
#pragma unroll
        for (int t = 0; t < 6; t++) {
            int nb = wv * 32 + (t & 1) * 16 + (t >> 1) * 128 + col16;
            bf16x8 bfr = *(const bf16x8*)((const char*)wipbf
                          + (size_t)ks * 24576 + (size_t)nb * 64 + quad * 16);
            acc[t] = __builtin_amdgcn_mfma_f32_16x16x32_bf16(af, bfr, acc[t], 0, 0, 0);
        }
    }

    // ---- P2: in-register attention for head wv, node quad ----
    const float ci = cinv[quad];
    const float cis = ci * QK_SCALE;

    const float bq0 = bip[wv * 32 + col16];
    const float bq1 = bip[wv * 32 + 16 + col16];
    const float bk0 = bip[128 + wv * 32 + col16];
    const float bk1 = bip[128 + wv * 32 + 16 + col16];
    const float bv0 = bip[256 + wv * 32 + col16];
    const float bv1 = bip[256 + wv * 32 + 16 + col16];
    const float bq0s = bq0 * QK_SCALE;
    const float bq1s = bq1 * QK_SCALE;

    float k0[5], k1[5];
#pragma unroll
    for (int s = 0; s < 4; s++) { k0[s] = acc[2][s] + bk0; k1[s] = acc[3][s] + bk1; }
    k0[4] = fmaf(acc[2][3], ci, bk0);
    k1[4] = fmaf(acc[3][3], ci, bk1);

    float wj[5] = {0.f, 0.f, 0.f, 0.f, 0.f};
#pragma unroll
    for (int i = 0; i < 5; i++) {
        float qi0 = (i < 4) ? fmaf(acc[0][i], QK_SCALE, bq0s)
                            : fmaf(acc[0][3], cis, bq0s);
        float qi1 = (i < 4) ? fmaf(acc[1][i], QK_SCALE, bq1s)
                            : fmaf(acc[1][3], cis, bq1s);
        float sv[5];
#pragma unroll
        for (int j = 0; j < 5; j++) sv[j] = qi0 * k0[j] + qi1 * k1[j];
#pragma unroll
        for (int j = 0; j < 5; j++) {
            sv[j] += __shfl_xor(sv[j], 1, 16);
            sv[j] += __shfl_xor(sv[j], 2, 16);
            sv[j] += __shfl_xor(sv[j], 4, 16);
            sv[j] += __shfl_xor(sv[j], 8, 16);
        }
        float m = sv[0];
#pragma unroll
        for (int j = 1; j < 5; j++) m = fmaxf(m, sv[j]);
        float e[5], l = 0.f;
#pragma unroll
        for (int j = 0; j < 5; j++) { e[j] = __expf(sv[j] - m); l += e[j]; }
        float inv = 0.2f / l;   // fold token-mean
#pragma unroll
        for (int j = 0; j < 5; j++) wj[j] = fmaf(e[j], inv, wj[j]);
    }

    float o0 = 0.f, o1 = 0.f;
#pragma unroll
    for (int j = 0; j < 5; j++) {
        float v0 = (j < 4) ? (acc[4][j] + bv0) : fmaf(acc[4][3], ci, bv0);
        float v1 = (j < 4) ? (acc[5][j] + bv1) : fmaf(acc[5][3], ci, bv1);
        o0 = fmaf(wj[j], v0, o0);
        o1 = fmaf(wj[j], v1, o1);
    }

    int node = node0 + quad;
    if (node < n_nodes) {
        omean_g[(size_t)node * C + wv * 32 + col16] = o0;
        omean_g[(size_t)node * C + wv * 32 + 16 + col16] = o1;
    }
}

// ---------------------------------------------------------------------------
// K5: out = self(d_out) + omean @ Wop^T + bop. 64-row blocks, 8x4 tiles.
// ---------------------------------------------------------------------------
__global__ __launch_bounds__(256, 3) void outproj_kernel(
    const float* __restrict__ omean_g, const float* __restrict__ Wop,
    const float* __restrict__ bop, float* __restrict__ out, int M)
{
    __shared__ float As[64 * 132];   // 33792 B
    __shared__ float Bs[128 * 36];   // 18432 B
    __shared__ float bopS[C];

    const int tid = threadIdx.x;
    const int m0 = blockIdx.x * 64;

    if (tid < C) bopS[tid] = bop[tid];

#pragma unroll
    for (int i = 0; i < 8; i++) {
        int id = tid + i * 256;
        int r = id >> 5, c4 = id & 31;
        float4 v = make_float4(0.f, 0.f, 0.f, 0.f);
        if (m0 + r < M) v = ((const float4*)omean_g)[(size_t)(m0 + r) * 32 + c4];
        *(float4*)&As[r * 132 + c4 * 4] = v;
    }

    const int tn = tid & 31;
    const int tm = tid >> 5;
    float acc[8][4];
#pragma unroll
    for (int m = 0; m < 8; m++)
#pragma unroll
        for (int j = 0; j < 4; j++) acc[m][j] = 0.f;

    for (int ks = 0; ks < 4; ks++) {
        __syncthreads();
#pragma unroll
        for (int i = 0; i < 4; i++) {
            int id = tid + i * 256;          // 1024 = 128 n x 8 q
            int n = id >> 3, q = id & 7;
            float4 w = ((const float4*)Wop)[(size_t)n * 32 + ks * 8 + q];
            *(float4*)&Bs[n * 36 + q * 4] = w;
        }
        __syncthreads();

        for (int k4 = 0; k4 < 8; k4++) {
            float4 a[8];
#pragma unroll
            for (int m = 0; m < 8; m++)
                a[m] = *(const float4*)&As[(tm * 8 + m) * 132 + ks * 32 + k4 * 4];
            float4 b[4];
#pragma unroll
            for (int j = 0; j < 4; j++)
                b[j] = *(const float4*)&Bs[(tn + 32 * j) * 36 + k4 * 4];
#pragma unroll
            for (int m = 0; m < 8; m++) {
                float4 av = a[m];
#pragma unroll
                for (int j = 0; j < 4; j++) {
                    float4 bv = b[j];
                    acc[m][j] += av.x * bv.x + av.y * bv.y
                               + av.z * bv.z + av.w * bv.w;
                }
            }
        }
    }

#pragma unroll
    for (int m = 0; m < 8; m++) {
        int row = m0 + tm * 8 + m;
        if (row < M) {
#pragma unroll
            for (int j = 0; j < 4; j++) {
                int col = tn + 32 * j;
                float* o = &out[(size_t)row * C + col];
                *o += acc[m][j] + bopS[col];
            }
        }
    }
}

// ---------------------------------------------------------------------------
extern "C" void kernel_launch(void* const* d_in, const int* in_sizes, int n_in,
                              void* d_out, int out_size, void* d_ws, size_t ws_size,
                              hipStream_t stream) {
    const float* x_user = (const float*)d_in[0];
    const float* x_item = (const float*)d_in[1];
    const int*   ei_u2i = (const int*)d_in[2];
    const int*   ei_i2u = (const int*)d_in[3];
    const float* W_nb   = (const float*)d_in[4];
    const float* b_nb   = (const float*)d_in[5];
    const float* W_self = (const float*)d_in[6];
    const float* b_self = (const float*)d_in[7];
    const float* Wip    = (const float*)d_in[8];
    const float* bip    = (const float*)d_in[9];
    const float* Wop    = (const float*)d_in[10];
    const float* bop    = (const float*)d_in[11];

    const int NU = in_sizes[0] / C;
    const int NI = in_sizes[1] / C;
    const int E1 = in_sizes[2] / 2;
    const int E2 = in_sizes[3] / 2;
    const int NTOT = NU + NI;

    float* out_user = (float*)d_out;
    float* out_item = out_user + (size_t)NU * C;

    // workspace: wipbf (24576 floats) | h_bf (rc ushorts) | self_bf (rc ushorts)
    //          | omean (rc floats) | curA (NI) | curB (NU) | csrA16 | csrB16
    float* ws = (float*)d_ws;
    short* wipbf            = (short*)ws;
    unsigned short* h_bf    = (unsigned short*)(ws + 24576);
    const size_t rc = (size_t)NTOT * C;
    unsigned short* self_bf = h_bf + rc;
    float* omean_all        = (float*)(self_bf + rc);
    int*   curA             = (int*)(omean_all + rc);   // item-side degrees (NI)
    int*   curB             = curA + NI;                // user-side degrees (NU)
    unsigned short* csrA16  = (unsigned short*)(curB + NU);
    unsigned short* csrB16  = csrA16 + E1;

    unsigned short* h_user_bf = h_bf;
    unsigned short* h_item_bf = h_bf + (size_t)NU * C;
    unsigned short* self_user_bf = self_bf;
    unsigned short* self_item_bf = self_bf + (size_t)NU * C;
    float* om_user = omean_all;
    float* om_item = omean_all + (size_t)NU * C;

    // K1: transform + prep (wip2bf + zero cur arrays)
    const int TB = (NTOT + 63) / 64;
    const int PB = 96 + (NTOT + 255) / 256;
    transform_prep_kernel<<<TB + PB, 256, 0, stream>>>(
        x_user, x_item, NU, NTOT, W_nb, b_nb, W_self, b_self,
        h_bf, self_bf, (float*)d_out, Wip, (unsigned*)wipbf,
        curA, NI, curB, NU, TB);

    // K2: merged histogram
    hist2_kernel<<<(E1 + E2 + 255) / 256, 256, 0, stream>>>(
        ei_u2i + E1, E1, curA, ei_i2u + E2, E2, curB);

    // K3: both scans in one launch
    scan2_kernel<<<2, 1024, 0, stream>>>(curA, NI, curB, NU);

    // K4: merged fill (ushort CSR)
    fill2_kernel<<<(E1 + E2 + 255) / 256, 256, 0, stream>>>(
        ei_u2i, ei_u2i + E1, E1, curA, csrA16,
        ei_i2u, ei_i2u + E2, E2, curB, csrB16);

    // K5a: direction B (item -> user)
    attn_fused_kernel<<<(NU + ATN - 1) / ATN, 256, 0, stream>>>(
        h_item_bf, csrB16, curB, self_user_bf, wipbf, bip, om_user, NU);

    // K5b: direction A (user -> item)
    attn_fused_kernel<<<(NI + ATN - 1) / ATN, 256, 0, stream>>>(
        h_user_bf, csrA16, curA, self_item_bf, wipbf, bip, om_item, NI);

    // K6: output projection
    outproj_kernel<<<(NTOT + 63) / 64, 256, 0, stream>>>(
        omean_all, Wop, bop, (float*)d_out, NTOT);
}

// Round 9
// 603.310 us; speedup vs baseline: 2.4855x; 1.1152x over previous
//
#include <hip/hip_runtime.h>
#include <hip/hip_bf16.h>

// ---------------------------------------------------------------------------
// AttentionHeteroConv. R16 = R15 with transform moved to MFMA.
// R15 lesson: transform_prep was ~135us (hidden at the top-5 cutoff) -- fp32
// vector GEMM at 2 blocks/CU. Now: [Wnb;Wself] pre-converted to a bf16
// B-image (64KB, L2-hot, wipbf-style layout [ks][256][32]); transform stages
// 64 x-rows as bf16 in LDS (17.4KB -> 4 blocks/CU) and runs 16x16x32 MFMA
// (wave w = cols w*64..+63; waves 0,1 -> h_bf, waves 2,3 -> self). Compute
// ~1us; kernel becomes memory-bound (~150MB traffic ~= 40us).
// Prep (wip2bf + wns2bf + zero curs) is a small K0 launch. 8 launches.
// attn (bf16 gather, R15) / CSR chain / outproj unchanged.
// ---------------------------------------------------------------------------

#define C 128
#define NHEAD 4
#define DH 32
#define QK_SCALE 0.17677669529663687f  // 1/sqrt(32)

typedef __attribute__((ext_vector_type(8))) short bf16x8;
typedef __attribute__((ext_vector_type(4))) short short4v;
typedef __attribute__((ext_vector_type(2))) short short2v;
typedef __attribute__((ext_vector_type(4))) float f32x4;

__device__ __forceinline__ short f2bf(float f) {
    unsigned u = __float_as_uint(f);
    unsigned r = u + 0x7FFFu + ((u >> 16) & 1u);   // round-to-nearest-even
    return (short)(r >> 16);
}

// ---------------------------------------------------------------------------
// K0: prep. Blocks [0,96): wip2bf [ks][384][32]. Blocks [96,160): wns2bf
// ([Wnb;Wself] -> [ks][256][32]). Blocks [160,...): zero curA/curB.
// ---------------------------------------------------------------------------
__global__ __launch_bounds__(256) void prep_kernel(
    const float* __restrict__ Wip, unsigned* __restrict__ img,
    const float* __restrict__ Wnb, const float* __restrict__ Wself,
    unsigned* __restrict__ imgW,
    int* __restrict__ curA, int nA, int* __restrict__ curB, int nB)
{
    const int tid = threadIdx.x;
    const int bid = (int)blockIdx.x;
    if (bid < 96) {
        int id = bid * 256 + tid;                // 24576 pair-slots
        int ks = id / (384 * 16);
        int rem = id - ks * (384 * 16);
        int n = rem >> 4, kk = rem & 15;
        float a = Wip[(size_t)n * C + ks * 32 + kk * 2 + 0];
        float b = Wip[(size_t)n * C + ks * 32 + kk * 2 + 1];
        unsigned pa = ((unsigned)(unsigned short)f2bf(a))
                    | (((unsigned)(unsigned short)f2bf(b)) << 16);
        img[(size_t)ks * 6144 + n * 16 + kk] = pa;
    } else if (bid < 160) {
        int id = (bid - 96) * 256 + tid;         // 16384 pair-slots
        int ks = id / (256 * 16);
        int rem = id - ks * (256 * 16);
        int n = rem >> 4, kk = rem & 15;
        const float* src = (n < 128) ? &Wnb[(size_t)n * C]
                                     : &Wself[(size_t)(n - 128) * C];
        float a = src[ks * 32 + kk * 2 + 0];
        float b = src[ks * 32 + kk * 2 + 1];
        unsigned pa = ((unsigned)(unsigned short)f2bf(a))
                    | (((unsigned)(unsigned short)f2bf(b)) << 16);
        imgW[(size_t)ks * 4096 + n * 16 + kk] = pa;
    } else {
        int i = (bid - 160) * 256 + tid;
        if (i < nA) curA[i] = 0;
        else if (i < nA + nB) curB[i - nA] = 0;
    }
}

// ---------------------------------------------------------------------------
// K1: transform via MFMA. 64 rows/block, 4 waves. Wave w computes output
// cols [w*64, w*64+64) (4 N-tiles): waves 0,1 -> h (bf16), 2,3 -> self
// (fp32 residual + bf16 copy). A: x rows staged bf16 in LDS [64][136].
// B: wnsbf image from L2. acc[4][4] f32x4, 64 MFMA/wave.
// ---------------------------------------------------------------------------
__global__ __launch_bounds__(256, 4) void transform_kernel(
    const float* __restrict__ xu, const float* __restrict__ xi,
    int NU, int NTOT,
    const unsigned short* __restrict__ wnsbf,
    const float* __restrict__ bnb, const float* __restrict__ bself,
    unsigned short* __restrict__ h_bf, unsigned short* __restrict__ self_bf,
    float* __restrict__ selfout)
{
    __shared__ char Ash[64 * 272];   // 17408 B
    __shared__ float biasS[256];

    const int tid = threadIdx.x;
    const int lane = tid & 63;
    const int wv = tid >> 6;
    const int row0 = blockIdx.x * 64;

    biasS[tid] = (tid < 128) ? bnb[tid] : bself[tid - 128];

    // stage A: 64 rows x 32 float4 -> bf16 LDS
#pragma unroll
    for (int i = 0; i < 8; i++) {
        int id = tid + i * 256;
        int r = id >> 5, c4 = id & 31;
        int row = row0 + r;
        float4 v = make_float4(0.f, 0.f, 0.f, 0.f);
        if (row < NTOT) {
            v = (row < NU) ? ((const float4*)xu)[(size_t)row * 32 + c4]
                           : ((const float4*)xi)[(size_t)(row - NU) * 32 + c4];
        }
        short4v b;
        b.x = f2bf(v.x); b.y = f2bf(v.y); b.z = f2bf(v.z); b.w = f2bf(v.w);
        *(short4v*)(Ash + r * 272 + c4 * 8) = b;
    }
    __syncthreads();

    const int quad = lane >> 4;
    const int col16 = lane & 15;

    f32x4 acc[4][4];   // [mtile][ntile]
#pragma unroll
    for (int mt = 0; mt < 4; mt++)
#pragma unroll
        for (int nt = 0; nt < 4; nt++) acc[mt][nt] = (f32x4){0.f, 0.f, 0.f, 0.f};

#pragma unroll
    for (int ks = 0; ks < 4; ks++) {
        bf16x8 bfv[4];
#pragma unroll
        for (int nt = 0; nt < 4; nt++) {
            int n = (wv * 4 + nt) * 16 + col16;
            bfv[nt] = *(const bf16x8*)((const char*)wnsbf
                        + (size_t)ks * 16384 + (size_t)n * 64 + quad * 16);
        }
#pragma unroll
        for (int mt = 0; mt < 4; mt++) {
            bf16x8 af = *(const bf16x8*)(Ash + (mt * 16 + col16) * 272
                                         + ks * 64 + quad * 16);
#pragma unroll
            for (int nt = 0; nt < 4; nt++)
                acc[mt][nt] = __builtin_amdgcn_mfma_f32_16x16x32_bf16(
                                  af, bfv[nt], acc[mt][nt], 0, 0, 0);
        }
    }

    // epilogue: C row = row0 + mt*16 + quad*4 + reg, col = (wv*4+nt)*16+col16
#pragma unroll
    for (int mt = 0; mt < 4; mt++) {
#pragma unroll
        for (int reg = 0; reg < 4; reg++) {
            int row = row0 + mt * 16 + quad * 4 + reg;
            if (row < NTOT) {
#pragma unroll
                for (int nt = 0; nt < 4; nt++) {
                    int col = (wv * 4 + nt) * 16 + col16;
                    float v = acc[mt][nt][reg] + biasS[col];
                    if (wv < 2) {   // wave-uniform branch
                        h_bf[(size_t)row * C + col] = (unsigned short)f2bf(v);
                    } else {
                        selfout[(size_t)row * C + (col - 128)] = v;
                        self_bf[(size_t)row * C + (col - 128)] = (unsigned short)f2bf(v);
                    }
                }
            }
        }
    }
}

// ---------------------------------------------------------------------------
// Merged histogram over both edge lists.
// ---------------------------------------------------------------------------
__global__ __launch_bounds__(256) void hist2_kernel(
    const int* __restrict__ dstA, int nA, int* __restrict__ curA,
    const int* __restrict__ dstB, int nB, int* __restrict__ curB)
{
    int i = blockIdx.x * 256 + threadIdx.x;
    if (i < nA) atomicAdd(&curA[dstA[i]], 1);
    else if (i < nA + nB) atomicAdd(&curB[dstB[i - nA]], 1);
}

// ---------------------------------------------------------------------------
// Scan: 2 blocks (block 0 -> curA/nA, block 1 -> curB/nB), 1024 threads,
// 4 elems/thread.
// ---------------------------------------------------------------------------
__global__ __launch_bounds__(1024) void scan2_kernel(
    int* __restrict__ curA, int nA, int* __restrict__ curB, int nB)
{
    int* cur = (blockIdx.x == 0) ? curA : curB;
    const int n = (blockIdx.x == 0) ? nA : nB;

    __shared__ int wsum[16];
    __shared__ int carryS;
    const int tid = threadIdx.x, lane = tid & 63, wv = tid >> 6;
    if (tid == 0) carryS = 0;
    __syncthreads();
    for (int base = 0; base < n; base += 4096) {
        int i0 = base + tid * 4;
        int v0 = 0, v1 = 0, v2 = 0, v3 = 0;
        if (i0 + 3 < n) {
            int4 t = *(const int4*)&cur[i0];
            v0 = t.x; v1 = t.y; v2 = t.z; v3 = t.w;
        } else {
            if (i0 < n) v0 = cur[i0];
            if (i0 + 1 < n) v1 = cur[i0 + 1];
            if (i0 + 2 < n) v2 = cur[i0 + 2];
            if (i0 + 3 < n) v3 = cur[i0 + 3];
        }
        int s1 = v0 + v1, s2 = s1 + v2, s3 = s2 + v3;
        int x = s3;
#pragma unroll
        for (int d = 1; d < 64; d <<= 1) {
            int t = __shfl_up(x, d, 64);
            if (lane >= d) x += t;
        }
        if (lane == 63) wsum[wv] = x;
        int carry = carryS;
        __syncthreads();
        int wpre = 0;
#pragma unroll
        for (int w2 = 0; w2 < 16; w2++) wpre += (w2 < wv) ? wsum[w2] : 0;
        int excl = x - s3 + wpre + carry;
        if (i0 + 3 < n) {
            int4 st; st.x = excl; st.y = excl + v0; st.z = excl + s1; st.w = excl + s2;
            *(int4*)&cur[i0] = st;
        } else {
            if (i0 < n) cur[i0] = excl;
            if (i0 + 1 < n) cur[i0 + 1] = excl + v0;
            if (i0 + 2 < n) cur[i0 + 2] = excl + s1;
            if (i0 + 3 < n) cur[i0 + 3] = excl + s2;
        }
        __syncthreads();
        if (tid == 0) {
            int t = 0;
#pragma unroll
            for (int w2 = 0; w2 < 16; w2++) t += wsum[w2];
            carryS = carry + t;
        }
        __syncthreads();
    }
}

// ---------------------------------------------------------------------------
// Merged fill: CSR entries stored as ushort (node ids < 65536).
// ---------------------------------------------------------------------------
__global__ __launch_bounds__(256) void fill2_kernel(
    const int* __restrict__ srcA, const int* __restrict__ dstA, int nA,
    int* __restrict__ curA, unsigned short* __restrict__ csrA,
    const int* __restrict__ srcB, const int* __restrict__ dstB, int nB,
    int* __restrict__ curB, unsigned short* __restrict__ csrB)
{
    int i = blockIdx.x * 256 + threadIdx.x;
    if (i < nA) {
        int p = atomicAdd(&curA[dstA[i]], 1);
        csrA[p] = (unsigned short)srcA[i];
    } else if (i < nA + nB) {
        int j = i - nA;
        int p = atomicAdd(&curB[dstB[j]], 1);
        csrB[p] = (unsigned short)srcB[j];
    }
}

// ---------------------------------------------------------------------------
// K4: fused gather-aggregate + bf16-MFMA qkv + in-register attention.
// 4 nodes/block, one direction per dispatch, 8 blocks/CU. bf16 h gather.
// ---------------------------------------------------------------------------
#define ATN 4

__global__ __launch_bounds__(256, 8) void attn_fused_kernel(
    const unsigned short* __restrict__ h_bf, const unsigned short* __restrict__ csr,
    const int* __restrict__ cur, const unsigned short* __restrict__ self_bf,
    const short* __restrict__ wipbf, const float* __restrict__ bip,
    float* __restrict__ omean_g, int n_nodes)
{
    __shared__ char Ash[16 * 272];   // bf16 A tile [16 rows][136 bf16]
    __shared__ float cinv[ATN];

    const int tid = threadIdx.x;
    const int lane = tid & 63;
    const int wv = tid >> 6;
    const int node0 = blockIdx.x * ATN;

    // ---- P0a: self rows (A row node*4+0) -- already bf16, direct copy ----
    if (tid < 128) {
        int r = tid >> 5, c4 = tid & 31;
        int node = node0 + r;
        short4v b = {0, 0, 0, 0};
        if (node < n_nodes)
            b = *(const short4v*)(self_bf + (size_t)node * C + c4 * 4);
        *(short4v*)(Ash + (r * 4) * 272 + c4 * 8) = b;
    }

    // ---- P0b: gather max/min/sum -> A rows wv*4+{1,2,3} (one node/wave) ----
    {
        const unsigned* h2 = (const unsigned*)h_bf;   // 64 uints per row
        int node = node0 + wv;
        float2 vs = make_float2(0.f, 0.f);
        float2 vmx = make_float2(-3.4e38f, -3.4e38f);
        float2 vmn = make_float2(3.4e38f, 3.4e38f);
        int deg = 0;
        if (node < n_nodes) {
            int start = (node == 0) ? 0 : cur[node - 1];
            int end = cur[node];
            deg = end - start;
            int e = start;
            for (; e + 8 <= end; e += 8) {
                unsigned v[8];
#pragma unroll
                for (int i = 0; i < 8; i++) {
                    int s = csr[e + i];
                    v[i] = h2[(size_t)s * 64 + lane];
                }
#pragma unroll
                for (int i = 0; i < 8; i++) {
                    float fx = __uint_as_float(v[i] << 16);
                    float fy = __uint_as_float(v[i] & 0xFFFF0000u);
                    vs.x += fx; vs.y += fy;
                    vmx.x = fmaxf(vmx.x, fx); vmx.y = fmaxf(vmx.y, fy);
                    vmn.x = fminf(vmn.x, fx); vmn.y = fminf(vmn.y, fy);
                }
            }
            if (e < end) {   // masked full-width tail: one latency round
                int last = end - 1;
                unsigned v[8];
#pragma unroll
                for (int i = 0; i < 8; i++) {
                    int idx = e + i;
                    int s = csr[(idx <= last) ? idx : last];
                    v[i] = h2[(size_t)s * 64 + lane];
                }
#pragma unroll
                for (int i = 0; i < 8; i++) {
                    if (e + i <= last) {   // wave-uniform
                        float fx = __uint_as_float(v[i] << 16);
                        float fy = __uint_as_float(v[i] & 0xFFFF0000u);
                        vs.x += fx; vs.y += fy;
                        vmx.x = fmaxf(vmx.x, fx); vmx.y = fmaxf(vmx.y, fy);
                        vmn.x = fminf(vmn.x, fx); vmn.y = fminf(vmn.y, fy);
                    }
                }
            }
        }
        if (deg == 0) {
            vmx = make_float2(0.f, 0.f);
            vmn = make_float2(0.f, 0.f);
        }
        short2v p;
        p.x = f2bf(vmx.x); p.y = f2bf(vmx.y);
        *(short2v*)(Ash + (wv * 4 + 1) * 272 + lane * 4) = p;
        p.x = f2bf(vmn.x); p.y = f2bf(vmn.y);
        *(short2v*)(Ash + (wv * 4 + 2) * 272 + lane * 4) = p;
        p.x = f2bf(vs.x); p.y = f2bf(vs.y);
        *(short2v*)(Ash + (wv * 4 + 3) * 272 + lane * 4) = p;
        if (lane == 0) cinv[wv] = 1.f / (float)max(deg, 1);
    }
    __syncthreads();   // the ONLY barrier

    // ---- P1: MFMA qkv for head wv only (M=16, N=6x16 tiles, K=128) ----
    const int quad = lane >> 4;      // node within block
    const int col16 = lane & 15;     // head-dim coordinate (cols c and c+16)

    f32x4 acc[6];
#pragma unroll
    for (int t = 0; t < 6; t++) acc[t] = (f32x4){0.f, 0.f, 0.f, 0.f};

#pragma unroll
    for (int ks = 0; ks < 4; ks++) {
        bf16x8 af = *(const bf16x8*)(Ash + col16 * 272 + ks * 64 + quad * 16);
#pragma unroll
        for (int t = 0; t < 6; t++) {
            int nb = wv * 32 + (t & 1) * 16 + (t >> 1) * 128 + col16;
            bf16x8 bfr = *(const bf16x8*)((const char*)wipbf
                          + (size_t)ks * 24576 + (size_t)nb * 64 + quad * 16);
            acc[t] = __builtin_amdgcn_mfma_f32_16x16x32_bf16(af, bfr, acc[t], 0, 0, 0);
        }
    }

    // ---- P2: in-register attention for head wv, node quad ----
    const float ci = cinv[quad];
    const float cis = ci * QK_SCALE;

    const float bq0 = bip[wv * 32 + col16];
    const float bq1 = bip[wv * 32 + 16 + col16];
    const float bk0 = bip[128 + wv * 32 + col16];
    const float bk1 = bip[128 + wv * 32 + 16 + col16];
    const float bv0 = bip[256 + wv * 32 + col16];
    const float bv1 = bip[256 + wv * 32 + 16 + col16];
    const float bq0s = bq0 * QK_SCALE;
    const float bq1s = bq1 * QK_SCALE;

    float k0[5], k1[5];
#pragma unroll
    for (int s = 0; s < 4; s++) { k0[s] = acc[2][s] + bk0; k1[s] = acc[3][s] + bk1; }
    k0[4] = fmaf(acc[2][3], ci, bk0);
    k1[4] = fmaf(acc[3][3], ci, bk1);

    float wj[5] = {0.f, 0.f, 0.f, 0.f, 0.f};
#pragma unroll
    for (int i = 0; i < 5; i++) {
        float qi0 = (i < 4) ? fmaf(acc[0][i], QK_SCALE, bq0s)
                            : fmaf(acc[0][3], cis, bq0s);
        float qi1 = (i < 4) ? fmaf(acc[1][i], QK_SCALE, bq1s)
                            : fmaf(acc[1][3], cis, bq1s);
        float sv[5];
#pragma unroll
        for (int j = 0; j < 5; j++) sv[j] = qi0 * k0[j] + qi1 * k1[j];
#pragma unroll
        for (int j = 0; j < 5; j++) {
            sv[j] += __shfl_xor(sv[j], 1, 16);
            sv[j] += __shfl_xor(sv[j], 2, 16);
            sv[j] += __shfl_xor(sv[j], 4, 16);
            sv[j] += __shfl_xor(sv[j], 8, 16);
        }
        float m = sv[0];
#pragma unroll
        for (int j = 1; j < 5; j++) m = fmaxf(m, sv[j]);
        float e[5], l = 0.f;
#pragma unroll
        for (int j = 0; j < 5; j++) { e[j] = __expf(sv[j] - m); l += e[j]; }
        float inv = 0.2f / l;   // fold token-mean
#pragma unroll
        for (int j = 0; j < 5; j++) wj[j] = fmaf(e[j], inv, wj[j]);
    }

    float o0 = 0.f, o1 = 0.f;
#pragma unroll
    for (int j = 0; j < 5; j++) {
        float v0 = (j < 4) ? (acc[4][j] + bv0) : fmaf(acc[4][3], ci, bv0);
        float v1 = (j < 4) ? (acc[5][j] + bv1) : fmaf(acc[5][3], ci, bv1);
        o0 = fmaf(wj[j], v0, o0);
        o1 = fmaf(wj[j], v1, o1);
    }

    int node = node0 + quad;
    if (node < n_nodes) {
        omean_g[(size_t)node * C + wv * 32 + col16] = o0;
        omean_g[(size_t)node * C + wv * 32 + 16 + col16] = o1;
    }
}

// ---------------------------------------------------------------------------
// K5: out = self(d_out) + omean @ Wop^T + bop. 64-row blocks, 8x4 tiles.
// ---------------------------------------------------------------------------
__global__ __launch_bounds__(256, 3) void outproj_kernel(
    const float* __restrict__ omean_g, const float* __restrict__ Wop,
    const float* __restrict__ bop, float* __restrict__ out, int M)
{
    __shared__ float As[64 * 132];   // 33792 B
    __shared__ float Bs[128 * 36];   // 18432 B
    __shared__ float bopS[C];

    const int tid = threadIdx.x;
    const int m0 = blockIdx.x * 64;

    if (tid < C) bopS[tid] = bop[tid];

#pragma unroll
    for (int i = 0; i < 8; i++) {
        int id = tid + i * 256;
        int r = id >> 5, c4 = id & 31;
        float4 v = make_float4(0.f, 0.f, 0.f, 0.f);
        if (m0 + r < M) v = ((const float4*)omean_g)[(size_t)(m0 + r) * 32 + c4];
        *(float4*)&As[r * 132 + c4 * 4] = v;
    }

    const int tn = tid & 31;
    const int tm = tid >> 5;
    float acc[8][4];
#pragma unroll
    for (int m = 0; m < 8; m++)
#pragma unroll
        for (int j = 0; j < 4; j++) acc[m][j] = 0.f;

    for (int ks = 0; ks < 4; ks++) {
        __syncthreads();
#pragma unroll
        for (int i = 0; i < 4; i++) {
            int id = tid + i * 256;          // 1024 = 128 n x 8 q
            int n = id >> 3, q = id & 7;
            float4 w = ((const float4*)Wop)[(size_t)n * 32 + ks * 8 + q];
            *(float4*)&Bs[n * 36 + q * 4] = w;
        }
        __syncthreads();

        for (int k4 = 0; k4 < 8; k4++) {
            float4 a[8];
#pragma unroll
            for (int m = 0; m < 8; m++)
                a[m] = *(const float4*)&As[(tm * 8 + m) * 132 + ks * 32 + k4 * 4];
            float4 b[4];
#pragma unroll
            for (int j = 0; j < 4; j++)
                b[j] = *(const float4*)&Bs[(tn + 32 * j) * 36 + k4 * 4];
#pragma unroll
            for (int m = 0; m < 8; m++) {
                float4 av = a[m];
#pragma unroll
                for (int j = 0; j < 4; j++) {
                    float4 bv = b[j];
                    acc[m][j] += av.x * bv.x + av.y * bv.y
                               + av.z * bv.z + av.w * bv.w;
                }
            }
        }
    }

#pragma unroll
    for (int m = 0; m < 8; m++) {
        int row = m0 + tm * 8 + m;
        if (row < M) {
#pragma unroll
            for (int j = 0; j < 4; j++) {
                int col = tn + 32 * j;
                float* o = &out[(size_t)row * C + col];
                *o += acc[m][j] + bopS[col];
            }
        }
    }
}

// ---------------------------------------------------------------------------
extern "C" void kernel_launch(void* const* d_in, const int* in_sizes, int n_in,
                              void* d_out, int out_size, void* d_ws, size_t ws_size,
                              hipStream_t stream) {
    const float* x_user = (const float*)d_in[0];
    const float* x_item = (const float*)d_in[1];
    const int*   ei_u2i = (const int*)d_in[2];
    const int*   ei_i2u = (const int*)d_in[3];
    const float* W_nb   = (const float*)d_in[4];
    const float* b_nb   = (const float*)d_in[5];
    const float* W_self = (const float*)d_in[6];
    const float* b_self = (const float*)d_in[7];
    const float* Wip    = (const float*)d_in[8];
    const float* bip    = (const float*)d_in[9];
    const float* Wop    = (const float*)d_in[10];
    const float* bop    = (const float*)d_in[11];

    const int NU = in_sizes[0] / C;
    const int NI = in_sizes[1] / C;
    const int E1 = in_sizes[2] / 2;
    const int E2 = in_sizes[3] / 2;
    const int NTOT = NU + NI;

    // workspace: wipbf (98304B = 24576 floats) | wnsbf (65536B = 16384 floats)
    //          | h_bf (rc ushorts) | self_bf (rc ushorts) | omean (rc floats)
    //          | curA (NI) | curB (NU) | csrA16 (E1) | csrB16 (E2)
    float* ws = (float*)d_ws;
    short* wipbf            = (short*)ws;
    unsigned short* wnsbf   = (unsigned short*)(ws + 24576);
    unsigned short* h_bf    = (unsigned short*)(ws + 24576 + 16384);
    const size_t rc = (size_t)NTOT * C;
    unsigned short* self_bf = h_bf + rc;
    float* omean_all        = (float*)(self_bf + rc);
    int*   curA             = (int*)(omean_all + rc);   // item-side degrees (NI)
    int*   curB             = curA + NI;                // user-side degrees (NU)
    unsigned short* csrA16  = (unsigned short*)(curB + NU);
    unsigned short* csrB16  = csrA16 + E1;

    unsigned short* h_user_bf = h_bf;
    unsigned short* h_item_bf = h_bf + (size_t)NU * C;
    unsigned short* self_user_bf = self_bf;
    unsigned short* self_item_bf = self_bf + (size_t)NU * C;
    float* om_user = omean_all;
    float* om_item = omean_all + (size_t)NU * C;

    // K0: prep (wip2bf + wns2bf + zero cur arrays)
    prep_kernel<<<160 + (NTOT + 255) / 256, 256, 0, stream>>>(
        Wip, (unsigned*)wipbf, W_nb, W_self, (unsigned*)wnsbf,
        curA, NI, curB, NU);

    // K1: MFMA transform
    transform_kernel<<<(NTOT + 63) / 64, 256, 0, stream>>>(
        x_user, x_item, NU, NTOT, wnsbf, b_nb, b_self,
        h_bf, self_bf, (float*)d_out);

    // K2: merged histogram
    hist2_kernel<<<(E1 + E2 + 255) / 256, 256, 0, stream>>>(
        ei_u2i + E1, E1, curA, ei_i2u + E2, E2, curB);

    // K3: both scans in one launch
    scan2_kernel<<<2, 1024, 0, stream>>>(curA, NI, curB, NU);

    // K4: merged fill (ushort CSR)
    fill2_kernel<<<(E1 + E2 + 255) / 256, 256, 0, stream>>>(
        ei_u2i, ei_u2i + E1, E1, curA, csrA16,
        ei_i2u, ei_i2u + E2, E2, curB, csrB16);

    // K5a: direction B (item -> user)
    attn_fused_kernel<<<(NU + ATN - 1) / ATN, 256, 0, stream>>>(
        h_item_bf, csrB16, curB, self_user_bf, wipbf, bip, om_user, NU);

    // K5b: direction A (user -> item)
    attn_fused_kernel<<<(NI + ATN - 1) / ATN, 256, 0, stream>>>(
        h_user_bf, csrA16, curA, self_item_bf, wipbf, bip, om_item, NI);

    // K6: output projection
    outproj_kernel<<<(NTOT + 63) / 64, 256, 0, stream>>>(
        omean_all, Wop, bop, (float*)d_out, NTOT);
}

// Round 10
// 579.919 us; speedup vs baseline: 2.5858x; 1.0403x over previous
//
#include <hip/hip_runtime.h>
#include <hip/hip_bf16.h>

// ---------------------------------------------------------------------------
// AttentionHeteroConv. R17 = R16 with the CSR chain hidden under busy kernels:
//  (1) hist merged as tail blocks of the transform launch (hist only needs
//      prep's zeroed curs, not transform's outputs) -- 1.6M atomics hide
//      under transform's streaming.
//  (2) fillA merged as tail blocks of the attnB launch (different direction's
//      buffers; attnA in the NEXT launch sees it complete).
//  (3) scan2 widened to 8 elems/thread (13 -> 7 barrier-bound iterations).
//  (4) fill launch now only fillB (half the edges) before attnB.
// 7 launches. attn/transform/outproj compute unchanged (R16-proven).
// ---------------------------------------------------------------------------

#define C 128
#define NHEAD 4
#define DH 32
#define QK_SCALE 0.17677669529663687f  // 1/sqrt(32)

typedef __attribute__((ext_vector_type(8))) short bf16x8;
typedef __attribute__((ext_vector_type(4))) short short4v;
typedef __attribute__((ext_vector_type(2))) short short2v;
typedef __attribute__((ext_vector_type(4))) float f32x4;

__device__ __forceinline__ short f2bf(float f) {
    unsigned u = __float_as_uint(f);
    unsigned r = u + 0x7FFFu + ((u >> 16) & 1u);   // round-to-nearest-even
    return (short)(r >> 16);
}

// ---------------------------------------------------------------------------
// K0: prep. Blocks [0,96): wip2bf [ks][384][32]. Blocks [96,160): wns2bf
// ([Wnb;Wself] -> [ks][256][32]). Blocks [160,...): zero curA/curB.
// ---------------------------------------------------------------------------
__global__ __launch_bounds__(256) void prep_kernel(
    const float* __restrict__ Wip, unsigned* __restrict__ img,
    const float* __restrict__ Wnb, const float* __restrict__ Wself,
    unsigned* __restrict__ imgW,
    int* __restrict__ curA, int nA, int* __restrict__ curB, int nB)
{
    const int tid = threadIdx.x;
    const int bid = (int)blockIdx.x;
    if (bid < 96) {
        int id = bid * 256 + tid;                // 24576 pair-slots
        int ks = id / (384 * 16);
        int rem = id - ks * (384 * 16);
        int n = rem >> 4, kk = rem & 15;
        float a = Wip[(size_t)n * C + ks * 32 + kk * 2 + 0];
        float b = Wip[(size_t)n * C + ks * 32 + kk * 2 + 1];
        unsigned pa = ((unsigned)(unsigned short)f2bf(a))
                    | (((unsigned)(unsigned short)f2bf(b)) << 16);
        img[(size_t)ks * 6144 + n * 16 + kk] = pa;
    } else if (bid < 160) {
        int id = (bid - 96) * 256 + tid;         // 16384 pair-slots
        int ks = id / (256 * 16);
        int rem = id - ks * (256 * 16);
        int n = rem >> 4, kk = rem & 15;
        const float* src = (n < 128) ? &Wnb[(size_t)n * C]
                                     : &Wself[(size_t)(n - 128) * C];
        float a = src[ks * 32 + kk * 2 + 0];
        float b = src[ks * 32 + kk * 2 + 1];
        unsigned pa = ((unsigned)(unsigned short)f2bf(a))
                    | (((unsigned)(unsigned short)f2bf(b)) << 16);
        imgW[(size_t)ks * 4096 + n * 16 + kk] = pa;
    } else {
        int i = (bid - 160) * 256 + tid;
        if (i < nA) curA[i] = 0;
        else if (i < nA + nB) curB[i - nA] = 0;
    }
}

// ---------------------------------------------------------------------------
// K1: MFMA transform + histogram tail blocks.
// Blocks [0,TB): 64-row transform tiles (R16). Blocks [TB,...): histogram,
// 4 edges/thread (edges [0,nEA) -> curA, [nEA,nEA+nEB) -> curB).
// ---------------------------------------------------------------------------
__global__ __launch_bounds__(256, 4) void transform_hist_kernel(
    const float* __restrict__ xu, const float* __restrict__ xi,
    int NU, int NTOT,
    const unsigned short* __restrict__ wnsbf,
    const float* __restrict__ bnb, const float* __restrict__ bself,
    unsigned short* __restrict__ h_bf, unsigned short* __restrict__ self_bf,
    float* __restrict__ selfout,
    const int* __restrict__ dstA, int nEA, int* __restrict__ curA,
    const int* __restrict__ dstB, int nEB, int* __restrict__ curB, int TB)
{
    const int tid = threadIdx.x;

    if ((int)blockIdx.x >= TB) {
        int gid = ((int)blockIdx.x - TB) * 256 + tid;
        int base = gid * 4;
#pragma unroll
        for (int k = 0; k < 4; k++) {
            int i = base + k;
            if (i < nEA) atomicAdd(&curA[dstA[i]], 1);
            else if (i < nEA + nEB) atomicAdd(&curB[dstB[i - nEA]], 1);
        }
        return;
    }

    __shared__ char Ash[64 * 272];   // 17408 B
    __shared__ float biasS[256];

    const int lane = tid & 63;
    const int wv = tid >> 6;
    const int row0 = blockIdx.x * 64;

    biasS[tid] = (tid < 128) ? bnb[tid] : bself[tid - 128];

    // stage A: 64 rows x 32 float4 -> bf16 LDS
#pragma unroll
    for (int i = 0; i < 8; i++) {
        int id = tid + i * 256;
        int r = id >> 5, c4 = id & 31;
        int row = row0 + r;
        float4 v = make_float4(0.f, 0.f, 0.f, 0.f);
        if (row < NTOT) {
            v = (row < NU) ? ((const float4*)xu)[(size_t)row * 32 + c4]
                           : ((const float4*)xi)[(size_t)(row - NU) * 32 + c4];
        }
        short4v b;
        b.x = f2bf(v.x); b.y = f2bf(v.y); b.z = f2bf(v.z); b.w = f2bf(v.w);
        *(short4v*)(Ash + r * 272 + c4 * 8) = b;
    }
    __syncthreads();

    const int quad = lane >> 4;
    const int col16 = lane & 15;

    f32x4 acc[4][4];   // [mtile][ntile]
#pragma unroll
    for (int mt = 0; mt < 4; mt++)
#pragma unroll
        for (int nt = 0; nt < 4; nt++) acc[mt][nt] = (f32x4){0.f, 0.f, 0.f, 0.f};

#pragma unroll
    for (int ks = 0; ks < 4; ks++) {
        bf16x8 bfv[4];
#pragma unroll
        for (int nt = 0; nt < 4; nt++) {
            int n = (wv * 4 + nt) * 16 + col16;
            bfv[nt] = *(const bf16x8*)((const char*)wnsbf
                        + (size_t)ks * 16384 + (size_t)n * 64 + quad * 16);
        }
#pragma unroll
        for (int mt = 0; mt < 4; mt++) {
            bf16x8 af = *(const bf16x8*)(Ash + (mt * 16 + col16) * 272
                                         + ks * 64 + quad * 16);
#pragma unroll
            for (int nt = 0; nt < 4; nt++)
                acc[mt][nt] = __builtin_amdgcn_mfma_f32_16x16x32_bf16(
                                  af, bfv[nt], acc[mt][nt], 0, 0, 0);
        }
    }

    // epilogue: C row = row0 + mt*16 + quad*4 + reg, col = (wv*4+nt)*16+col16
#pragma unroll
    for (int mt = 0; mt < 4; mt++) {
#pragma unroll
        for (int reg = 0; reg < 4; reg++) {
            int row = row0 + mt * 16 + quad * 4 + reg;
            if (row < NTOT) {
#pragma unroll
                for (int nt = 0; nt < 4; nt++) {
                    int col = (wv * 4 + nt) * 16 + col16;
                    float v = acc[mt][nt][reg] + biasS[col];
                    if (wv < 2) {   // wave-uniform branch
                        h_bf[(size_t)row * C + col] = (unsigned short)f2bf(v);
                    } else {
                        selfout[(size_t)row * C + (col - 128)] = v;
                        self_bf[(size_t)row * C + (col - 128)] = (unsigned short)f2bf(v);
                    }
                }
            }
        }
    }
}

// ---------------------------------------------------------------------------
// Scan: 2 blocks (block 0 -> curA/nA, block 1 -> curB/nB), 1024 threads,
// 8 elems/thread (8192/iteration -> 7 iterations at n=50000).
// ---------------------------------------------------------------------------
__global__ __launch_bounds__(1024) void scan2_kernel(
    int* __restrict__ curA, int nA, int* __restrict__ curB, int nB)
{
    int* cur = (blockIdx.x == 0) ? curA : curB;
    const int n = (blockIdx.x == 0) ? nA : nB;

    __shared__ int wsum[16];
    __shared__ int carryS;
    const int tid = threadIdx.x, lane = tid & 63, wv = tid >> 6;
    if (tid == 0) carryS = 0;
    __syncthreads();
    for (int base = 0; base < n; base += 8192) {
        int i0 = base + tid * 8;
        int v[8];
        if (i0 + 7 < n) {
            int4 a = *(const int4*)&cur[i0];
            int4 b = *(const int4*)&cur[i0 + 4];
            v[0] = a.x; v[1] = a.y; v[2] = a.z; v[3] = a.w;
            v[4] = b.x; v[5] = b.y; v[6] = b.z; v[7] = b.w;
        } else {
#pragma unroll
            for (int k = 0; k < 8; k++) v[k] = (i0 + k < n) ? cur[i0 + k] : 0;
        }
        int s[8];
        s[0] = v[0];
#pragma unroll
        for (int k = 1; k < 8; k++) s[k] = s[k - 1] + v[k];
        int x = s[7];
#pragma unroll
        for (int d = 1; d < 64; d <<= 1) {
            int t = __shfl_up(x, d, 64);
            if (lane >= d) x += t;
        }
        if (lane == 63) wsum[wv] = x;
        int carry = carryS;
        __syncthreads();
        int wpre = 0;
#pragma unroll
        for (int w2 = 0; w2 < 16; w2++) wpre += (w2 < wv) ? wsum[w2] : 0;
        int excl = x - s[7] + wpre + carry;
        if (i0 + 7 < n) {
            int4 a, b;
            a.x = excl;        a.y = excl + s[0]; a.z = excl + s[1]; a.w = excl + s[2];
            b.x = excl + s[3]; b.y = excl + s[4]; b.z = excl + s[5]; b.w = excl + s[6];
            *(int4*)&cur[i0] = a;
            *(int4*)&cur[i0 + 4] = b;
        } else {
#pragma unroll
            for (int k = 0; k < 8; k++)
                if (i0 + k < n) cur[i0 + k] = excl + (k ? s[k - 1] : 0);
        }
        __syncthreads();
        if (tid == 0) {
            int t = 0;
#pragma unroll
            for (int w2 = 0; w2 < 16; w2++) t += wsum[w2];
            carryS = carry + t;
        }
        __syncthreads();
    }
}

// ---------------------------------------------------------------------------
// fillB: one direction only, 4 edges/thread.
// ---------------------------------------------------------------------------
__global__ __launch_bounds__(256) void fill_kernel(
    const int* __restrict__ src, const int* __restrict__ dst, int nE,
    int* __restrict__ cur, unsigned short* __restrict__ csr)
{
    int base = (blockIdx.x * 256 + threadIdx.x) * 4;
#pragma unroll
    for (int k = 0; k < 4; k++) {
        int i = base + k;
        if (i < nE) {
            int p = atomicAdd(&cur[dst[i]], 1);
            csr[p] = (unsigned short)src[i];
        }
    }
}

// ---------------------------------------------------------------------------
// K4/K5: fused gather-aggregate + bf16-MFMA qkv + in-register attention,
// with optional fill tail blocks (blocks >= nAttnBlocks fill the OTHER
// direction's CSR -- hidden under this dispatch, consumed by the next).
// 4 nodes/block, 8 blocks/CU, bf16 h gather.
// ---------------------------------------------------------------------------
#define ATN 4

__global__ __launch_bounds__(256, 8) void attn_fused_kernel(
    const unsigned short* __restrict__ h_bf, const unsigned short* __restrict__ csr,
    const int* __restrict__ cur, const unsigned short* __restrict__ self_bf,
    const short* __restrict__ wipbf, const float* __restrict__ bip,
    float* __restrict__ omean_g, int n_nodes, int nAttnBlocks,
    const int* __restrict__ srcF, const int* __restrict__ dstF, int nEF,
    int* __restrict__ curF, unsigned short* __restrict__ csrF)
{
    __shared__ char Ash[16 * 272];   // bf16 A tile [16 rows][136 bf16]
    __shared__ float cinv[ATN];

    const int tid = threadIdx.x;

    if ((int)blockIdx.x >= nAttnBlocks) {
        // fill tail for the other direction
        int base = (((int)blockIdx.x - nAttnBlocks) * 256 + tid) * 4;
#pragma unroll
        for (int k = 0; k < 4; k++) {
            int i = base + k;
            if (i < nEF) {
                int p = atomicAdd(&curF[dstF[i]], 1);
                csrF[p] = (unsigned short)srcF[i];
            }
        }
        return;
    }

    const int lane = tid & 63;
    const int wv = tid >> 6;
    const int node0 = blockIdx.x * ATN;

    // ---- P0a: self rows (A row node*4+0) -- already bf16, direct copy ----
    if (tid < 128) {
        int r = tid >> 5, c4 = tid & 31;
        int node = node0 + r;
        short4v b = {0, 0, 0, 0};
        if (node < n_nodes)
            b = *(const short4v*)(self_bf + (size_t)node * C + c4 * 4);
        *(short4v*)(Ash + (r * 4) * 272 + c4 * 8) = b;
    }

    // ---- P0b: gather max/min/sum -> A rows wv*4+{1,2,3} (one node/wave) ----
    {
        const unsigned* h2 = (const unsigned*)h_bf;   // 64 uints per row
        int node = node0 + wv;
        float2 vs = make_float2(0.f, 0.f);
        float2 vmx = make_float2(-3.4e38f, -3.4e38f);
        float2 vmn = make_float2(3.4e38f, 3.4e38f);
        int deg = 0;
        if (node < n_nodes) {
            int start = (node == 0) ? 0 : cur[node - 1];
            int end = cur[node];
            deg = end - start;
            int e = start;
            for (; e + 8 <= end; e += 8) {
                unsigned v[8];
#pragma unroll
                for (int i = 0; i < 8; i++) {
                    int s = csr[e + i];
                    v[i] = h2[(size_t)s * 64 + lane];
                }
#pragma unroll
                for (int i = 0; i < 8; i++) {
                    float fx = __uint_as_float(v[i] << 16);
                    float fy = __uint_as_float(v[i] & 0xFFFF0000u);
                    vs.x += fx; vs.y += fy;
                    vmx.x = fmaxf(vmx.x, fx); vmx.y = fmaxf(vmx.y, fy);
                    vmn.x = fminf(vmn.x, fx); vmn.y = fminf(vmn.y, fy);
                }
            }
            if (e < end) {   // masked full-width tail: one latency round
                int last = end - 1;
                unsigned v[8];
#pragma unroll
                for (int i = 0; i < 8; i++) {
                    int idx = e + i;
                    int s = csr[(idx <= last) ? idx : last];
                    v[i] = h2[(size_t)s * 64 + lane];
                }
#pragma unroll
                for (int i = 0; i < 8; i++) {
                    if (e + i <= last) {   // wave-uniform
                        float fx = __uint_as_float(v[i] << 16);
                        float fy = __uint_as_float(v[i] & 0xFFFF0000u);
                        vs.x += fx; vs.y += fy;
                        vmx.x = fmaxf(vmx.x, fx); vmx.y = fmaxf(vmx.y, fy);
                        vmn.x = fminf(vmn.x, fx); vmn.y = fminf(vmn.y, fy);
                    }
                }
            }
        }
        if (deg == 0) {
            vmx = make_float2(0.f, 0.f);
            vmn = make_float2(0.f, 0.f);
        }
        short2v p;
        p.x = f2bf(vmx.x); p.y = f2bf(vmx.y);
        *(short2v*)(Ash + (wv * 4 + 1) * 272 + lane * 4) = p;
        p.x = f2bf(vmn.x); p.y = f2bf(vmn.y);
        *(short2v*)(Ash + (wv * 4 + 2) * 272 + lane * 4) = p;
        p.x = f2bf(vs.x); p.y = f2bf(vs.y);
        *(short2v*)(Ash + (wv * 4 + 3) * 272 + lane * 4) = p;
        if (lane == 0) cinv[wv] = 1.f / (float)max(deg, 1);
    }
    __syncthreads();   // the ONLY barrier

    // ---- P1: MFMA qkv for head wv only (M=16, N=6x16 tiles, K=128) ----
    const int quad = lane >> 4;      // node within block
    const int col16 = lane & 15;     // head-dim coordinate (cols c and c+16)

    f32x4 acc[6];
#pragma unroll
    for (int t = 0; t < 6; t++) acc[t] = (f32x4){0.f, 0.f, 0.f, 0.f};

#pragma unroll
    for (int ks = 0; ks < 4; ks++) {
        bf16x8 af = *(const bf16x8*)(Ash + col16 * 272 + ks * 64 + quad * 16);
#pragma unroll
        for (int t = 0; t < 6; t++) {
            int nb = wv * 32 + (t & 1) * 16 + (t >> 1) * 128 + col16;
            bf16x8 bfr = *(const bf16x8*)((const char*)wipbf
                          + (size_t)ks * 24576 + (size_t)nb * 64 + quad * 16);
            acc[t] = __builtin_amdgcn_mfma_f32_16x16x32_bf16(af, bfr, acc[t], 0, 0, 0);
        }
    }

    // ---- P2: in-register attention for head wv, node quad ----
    const float ci = cinv[quad];
    const float cis = ci * QK_SCALE;

    const float bq0 = bip[wv * 32 + col16];
    const float bq1 = bip[wv * 32 + 16 + col16];
    const float bk0 = bip[128 + wv * 32 + col16];
    const float bk1 = bip[128 + wv * 32 + 16 + col16];
    const float bv0 = bip[256 + wv * 32 + col16];
    const float bv1 = bip[256 + wv * 32 + 16 + col16];
    const float bq0s = bq0 * QK_SCALE;
    const float bq1s = bq1 * QK_SCALE;

    float k0[5], k1[5];
#pragma unroll
    for (int s = 0; s < 4; s++) { k0[s] = acc[2][s] + bk0; k1[s] = acc[3][s] + bk1; }
    k0[4] = fmaf(acc[2][3], ci, bk0);
    k1[4] = fmaf(acc[3][3], ci, bk1);

    float wj[5] = {0.f, 0.f, 0.f, 0.f, 0.f};
#pragma unroll
    for (int i = 0; i < 5; i++) {
        float qi0 = (i < 4) ? fmaf(acc[0][i], QK_SCALE, bq0s)
                            : fmaf(acc[0][3], cis, bq0s);
        float qi1 = (i < 4) ? fmaf(acc[1][i], QK_SCALE, bq1s)
                            : fmaf(acc[1][3], cis, bq1s);
        float sv[5];
#pragma unroll
        for (int j = 0; j < 5; j++) sv[j] = qi0 * k0[j] + qi1 * k1[j];
#pragma unroll
        for (int j = 0; j < 5; j++) {
            sv[j] += __shfl_xor(sv[j], 1, 16);
            sv[j] += __shfl_xor(sv[j], 2, 16);
            sv[j] += __shfl_xor(sv[j], 4, 16);
            sv[j] += __shfl_xor(sv[j], 8, 16);
        }
        float m = sv[0];
#pragma unroll
        for (int j = 1; j < 5; j++) m = fmaxf(m, sv[j]);
        float e[5], l = 0.f;
#pragma unroll
        for (int j = 0; j < 5; j++) { e[j] = __expf(sv[j] - m); l += e[j]; }
        float inv = 0.2f / l;   // fold token-mean
#pragma unroll
        for (int j = 0; j < 5; j++) wj[j] = fmaf(e[j], inv, wj[j]);
    }

    float o0 = 0.f, o1 = 0.f;
#pragma unroll
    for (int j = 0; j < 5; j++) {
        float v0 = (j < 4) ? (acc[4][j] + bv0) : fmaf(acc[4][3], ci, bv0);
        float v1 = (j < 4) ? (acc[5][j] + bv1) : fmaf(acc[5][3], ci, bv1);
        o0 = fmaf(wj[j], v0, o0);
        o1 = fmaf(wj[j], v1, o1);
    }

    int node = node0 + quad;
    if (node < n_nodes) {
        omean_g[(size_t)node * C + wv * 32 + col16] = o0;
        omean_g[(size_t)node * C + wv * 32 + 16 + col16] = o1;
    }
}

// ---------------------------------------------------------------------------
// K6: out = self(d_out) + omean @ Wop^T + bop. 64-row blocks, 8x4 tiles.
// ---------------------------------------------------------------------------
__global__ __launch_bounds__(256, 3) void outproj_kernel(
    const float* __restrict__ omean_g, const float* __restrict__ Wop,
    const float* __restrict__ bop, float* __restrict__ out, int M)
{
    __shared__ float As[64 * 132];   // 33792 B
    __shared__ float Bs[128 * 36];   // 18432 B
    __shared__ float bopS[C];

    const int tid = threadIdx.x;
    const int m0 = blockIdx.x * 64;

    if (tid < C) bopS[tid] = bop[tid];

#pragma unroll
    for (int i = 0; i < 8; i++) {
        int id = tid + i * 256;
        int r = id >> 5, c4 = id & 31;
        float4 v = make_float4(0.f, 0.f, 0.f, 0.f);
        if (m0 + r < M) v = ((const float4*)omean_g)[(size_t)(m0 + r) * 32 + c4];
        *(float4*)&As[r * 132 + c4 * 4] = v;
    }

    const int tn = tid & 31;
    const int tm = tid >> 5;
    float acc[8][4];
#pragma unroll
    for (int m = 0; m < 8; m++)
#pragma unroll
        for (int j = 0; j < 4; j++) acc[m][j] = 0.f;

    for (int ks = 0; ks < 4; ks++) {
        __syncthreads();
#pragma unroll
        for (int i = 0; i < 4; i++) {
            int id = tid + i * 256;          // 1024 = 128 n x 8 q
            int n = id >> 3, q = id & 7;
            float4 w = ((const float4*)Wop)[(size_t)n * 32 + ks * 8 + q];
            *(float4*)&Bs[n * 36 + q * 4] = w;
        }
        __syncthreads();

        for (int k4 = 0; k4 < 8; k4++) {
            float4 a[8];
#pragma unroll
            for (int m = 0; m < 8; m++)
                a[m] = *(const float4*)&As[(tm * 8 + m) * 132 + ks * 32 + k4 * 4];
            float4 b[4];
#pragma unroll
            for (int j = 0; j < 4; j++)
                b[j] = *(const float4*)&Bs[(tn + 32 * j) * 36 + k4 * 4];
#pragma unroll
            for (int m = 0; m < 8; m++) {
                float4 av = a[m];
#pragma unroll
                for (int j = 0; j < 4; j++) {
                    float4 bv = b[j];
                    acc[m][j] += av.x * bv.x + av.y * bv.y
                               + av.z * bv.z + av.w * bv.w;
                }
            }
        }
    }

#pragma unroll
    for (int m = 0; m < 8; m++) {
        int row = m0 + tm * 8 + m;
        if (row < M) {
#pragma unroll
            for (int j = 0; j < 4; j++) {
                int col = tn + 32 * j;
                float* o = &out[(size_t)row * C + col];
                *o += acc[m][j] + bopS[col];
            }
        }
    }
}

// ---------------------------------------------------------------------------
extern "C" void kernel_launch(void* const* d_in, const int* in_sizes, int n_in,
                              void* d_out, int out_size, void* d_ws, size_t ws_size,
                              hipStream_t stream) {
    const float* x_user = (const float*)d_in[0];
    const float* x_item = (const float*)d_in[1];
    const int*   ei_u2i = (const int*)d_in[2];
    const int*   ei_i2u = (const int*)d_in[3];
    const float* W_nb   = (const float*)d_in[4];
    const float* b_nb   = (const float*)d_in[5];
    const float* W_self = (const float*)d_in[6];
    const float* b_self = (const float*)d_in[7];
    const float* Wip    = (const float*)d_in[8];
    const float* bip    = (const float*)d_in[9];
    const float* Wop    = (const float*)d_in[10];
    const float* bop    = (const float*)d_in[11];

    const int NU = in_sizes[0] / C;
    const int NI = in_sizes[1] / C;
    const int E1 = in_sizes[2] / 2;
    const int E2 = in_sizes[3] / 2;
    const int NTOT = NU + NI;

    // workspace: wipbf (24576 floats) | wnsbf (16384 floats-worth) | h_bf
    //          | self_bf | omean | curA | curB | csrA16 | csrB16
    float* ws = (float*)d_ws;
    short* wipbf            = (short*)ws;
    unsigned short* wnsbf   = (unsigned short*)(ws + 24576);
    unsigned short* h_bf    = (unsigned short*)(ws + 24576 + 16384);
    const size_t rc = (size_t)NTOT * C;
    unsigned short* self_bf = h_bf + rc;
    float* omean_all        = (float*)(self_bf + rc);
    int*   curA             = (int*)(omean_all + rc);   // item-side degrees (NI)
    int*   curB             = curA + NI;                // user-side degrees (NU)
    unsigned short* csrA16  = (unsigned short*)(curB + NU);
    unsigned short* csrB16  = csrA16 + E1;

    unsigned short* h_user_bf = h_bf;
    unsigned short* h_item_bf = h_bf + (size_t)NU * C;
    unsigned short* self_user_bf = self_bf;
    unsigned short* self_item_bf = self_bf + (size_t)NU * C;
    float* om_user = omean_all;
    float* om_item = omean_all + (size_t)NU * C;

    // K0: prep (wip2bf + wns2bf + zero cur arrays)
    prep_kernel<<<160 + (NTOT + 255) / 256, 256, 0, stream>>>(
        Wip, (unsigned*)wipbf, W_nb, W_self, (unsigned*)wnsbf,
        curA, NI, curB, NU);

    // K1: MFMA transform + hist tail blocks
    const int TB = (NTOT + 63) / 64;
    const int HB = (E1 + E2 + 1023) / 1024;
    transform_hist_kernel<<<TB + HB, 256, 0, stream>>>(
        x_user, x_item, NU, NTOT, wnsbf, b_nb, b_self,
        h_bf, self_bf, (float*)d_out,
        ei_u2i + E1, E1, curA, ei_i2u + E2, E2, curB, TB);

    // K2: both scans in one launch
    scan2_kernel<<<2, 1024, 0, stream>>>(curA, NI, curB, NU);

    // K3: fillB only (dir B consumed next)
    fill_kernel<<<(E2 + 1023) / 1024, 256, 0, stream>>>(
        ei_i2u, ei_i2u + E2, E2, curB, csrB16);

    // K4: attn dir B (item -> user) + fillA tail blocks (hidden)
    const int nbB = (NU + ATN - 1) / ATN;
    const int FBA = (E1 + 1023) / 1024;
    attn_fused_kernel<<<nbB + FBA, 256, 0, stream>>>(
        h_item_bf, csrB16, curB, self_user_bf, wipbf, bip, om_user, NU, nbB,
        ei_u2i, ei_u2i + E1, E1, curA, csrA16);

    // K5: attn dir A (user -> item), no fill tail
    const int nbA = (NI + ATN - 1) / ATN;
    attn_fused_kernel<<<nbA, 256, 0, stream>>>(
        h_user_bf, csrA16, curA, self_item_bf, wipbf, bip, om_item, NI, nbA,
        (const int*)nullptr, (const int*)nullptr, 0,
        (int*)nullptr, (unsigned short*)nullptr);

    // K6: output projection
    outproj_kernel<<<(NTOT + 63) / 64, 256, 0, stream>>>(
        omean_all, Wop, bop, (float*)d_out, NTOT);
}